// Round 11
// baseline (340.639 us; speedup 1.0000x reference)
//
#include <hip/hip_runtime.h>
#include <stdint.h>

#define N_BATCH 8
#define A_ 3
#define H_ 336
#define W_ 336
#define HW_ (H_*W_)        // 112896
#define M_ (A_*HW_)        // 338688
#define K_TOP 2000
#define POST_N 1000
#define NMS_THR_ 0.7f
#define NEG_ (-1e9f)
#define VALID_THR_ (-5e8f)
#define CAND_CAP 4096
#define NBINS 4096
#define BIN_SHIFT 20       // top 12 bits: sign+exp+3 mantissa
#define HBLK 32            // histogram/compact blocks per batch (256 blocks total)
#define SEG_ (M_/HBLK)     // 10584
#define XCLIP 4.135166556742356f  // log(1000/16)

#define NPAD 2048          // boxes padded to 32 chunks of 64
#define NW 32              // u64 words per adjacency row (ring UNPADDED: global_load_lds needs contiguity)
#define NCHUNK 32
#define RING 4             // ring slots (chunk c -> slot c&3)

typedef unsigned long long u64;

__device__ __forceinline__ unsigned int flip_key(float x) {
    unsigned int u = __float_as_uint(x);
    return (u & 0x80000000u) ? ~u : (u | 0x80000000u);
}
__device__ __forceinline__ float unflip_key(unsigned int k) {
    unsigned int u = (k & 0x80000000u) ? (k & 0x7fffffffu) : ~k;
    return __uint_as_float(u);
}

// Direct global->LDS DMA, 16 B/lane, no VGPR round-trip.
__device__ __forceinline__ void gload_lds16(const u64* g, u64* l) {
    __builtin_amdgcn_global_load_lds(
        (const __attribute__((address_space(1))) unsigned int*)(const void*)g,
        (__attribute__((address_space(3))) unsigned int*)(void*)l,
        16, 0, 0);
}

// ---------------- K1: per-block LDS histogram -> private u16 sub-hist (no global atomics) ----------------
__global__ __launch_bounds__(512) void k_hist(const float* __restrict__ logits,
                                              unsigned short* __restrict__ ghist) {
    __shared__ unsigned int h[NBINS];  // 16 KiB
    int n = blockIdx.y, b = blockIdx.x;
    for (int i = threadIdx.x; i < NBINS; i += 512) h[i] = 0;
    __syncthreads();
    const float4* lp = (const float4*)(logits + (size_t)n * M_ + (size_t)b * SEG_);
    const int nq = SEG_ / 4;                 // 2646
    for (int q = threadIdx.x; q < nq; q += 512) {
        float4 v = lp[q];
        atomicAdd(&h[flip_key(v.x) >> BIN_SHIFT], 1u);
        atomicAdd(&h[flip_key(v.y) >> BIN_SHIFT], 1u);
        atomicAdd(&h[flip_key(v.z) >> BIN_SHIFT], 1u);
        atomicAdd(&h[flip_key(v.w) >> BIN_SHIFT], 1u);
    }
    __syncthreads();
    unsigned short* gp = ghist + ((size_t)n * HBLK + b) * NBINS;
    for (int i = threadIdx.x; i < NBINS; i += 512) gp[i] = (unsigned short)h[i];
}

// ---------------- K1b: sum sub-hists, find threshold bin B per batch ----------------
__global__ __launch_bounds__(256) void k_scan(const unsigned short* __restrict__ ghist,
                                              unsigned int* __restrict__ thresh) {
    int n = blockIdx.x;
    int t = threadIdx.x;
    __shared__ unsigned int binsum[NBINS];
    __shared__ unsigned int part[256];
    __shared__ unsigned int scanb[256];
    const unsigned short* base = ghist + (size_t)n * HBLK * NBINS;
    for (int i = t; i < NBINS; i += 256) {
        unsigned int s = 0;
        #pragma unroll 8
        for (int b = 0; b < HBLK; ++b) s += base[(size_t)b * NBINS + i];
        binsum[i] = s;
    }
    __syncthreads();
    // chunk t covers bins [NBINS-16*(t+1), NBINS-16*t) — descending chunks
    int hi = NBINS - 16 * t;
    int lo = hi - 16;
    unsigned int s = 0;
    for (int b = lo; b < hi; ++b) s += binsum[b];
    part[t] = s;
    scanb[t] = s;
    __syncthreads();
    for (int off = 1; off < 256; off <<= 1) {
        unsigned int v = scanb[t];
        unsigned int addv = (t >= off) ? scanb[t - off] : 0u;
        __syncthreads();
        scanb[t] = v + addv;
        __syncthreads();
    }
    unsigned int incl = scanb[t];
    unsigned int prefix = incl - part[t];
    if (prefix < K_TOP && incl >= K_TOP) {
        unsigned int acc = prefix;
        for (int b = hi - 1; b >= lo; --b) {
            unsigned int c = binsum[b];
            if (acc + c >= K_TOP) {
                thresh[n] = (unsigned int)b;
                break;
            }
            acc += c;
        }
    }
}

// ---------------- K2: compact candidates via LDS buffer + 1 global atomic per block ----------------
__global__ __launch_bounds__(512) void k_compact(const float* __restrict__ logits,
                                                 const unsigned int* __restrict__ thresh,
                                                 unsigned int* __restrict__ cnt,
                                                 u64* __restrict__ cand) {
    __shared__ u64 buf[CAND_CAP];  // 32 KiB
    __shared__ unsigned int lcnt;
    __shared__ unsigned int gbase;
    int n = blockIdx.y, b = blockIdx.x;
    unsigned int B = thresh[n];
    if (threadIdx.x == 0) lcnt = 0;
    __syncthreads();
    const int qbase = b * SEG_;
    const float4* lp = (const float4*)(logits + (size_t)n * M_ + (size_t)qbase);
    const int nq = SEG_ / 4;
    for (int q = threadIdx.x; q < nq; q += 512) {
        float4 v = lp[q];
        float vv[4] = {v.x, v.y, v.z, v.w};
        #pragma unroll
        for (int e = 0; e < 4; ++e) {
            unsigned int u = flip_key(vv[e]);
            if ((u >> BIN_SHIFT) >= B) {
                int qq = qbase + q * 4 + e;
                int a = qq / HW_;
                int hw = qq - a * HW_;
                unsigned int m = (unsigned int)(hw * A_ + a);  // score-order index
                unsigned int pos = atomicAdd(&lcnt, 1u);
                if (pos < CAND_CAP)
                    buf[pos] = ((u64)u << 32) | (unsigned int)(~m);
            }
        }
    }
    __syncthreads();
    unsigned int L = (lcnt < CAND_CAP) ? lcnt : CAND_CAP;
    if (threadIdx.x == 0) gbase = atomicAdd(&cnt[n], L);
    __syncthreads();
    u64* cp = cand + (size_t)n * CAND_CAP;
    for (unsigned int i = threadIdx.x; i < L; i += 512) {
        unsigned int pos = gbase + i;
        if (pos < CAND_CAP) cp[pos] = buf[i];
    }
}

// ---------------- K3: rank-by-counting (replaces bitonic sort) + fused decode ----------------
// Keys are unique -> rank(i) = #{j: key_j > key_i} is a permutation; rank < K_TOP
// candidates ARE the sorted top-2000 (desc, ties by smaller m — matches lax.top_k).
__global__ __launch_bounds__(512) void k_rank(const u64* __restrict__ cand,
                                              const unsigned int* __restrict__ cnt,
                                              const float* __restrict__ anchors,
                                              const float* __restrict__ breg,
                                              float4* __restrict__ boxes,
                                              float* __restrict__ scores,
                                              float* __restrict__ areas) {
    __shared__ u64 keys[CAND_CAP];          // 32 KiB
    __shared__ unsigned short psum[512];
    int n = blockIdx.y;
    int bx = blockIdx.x;
    unsigned int Cu = cnt[n];
    int C = (Cu < CAND_CAP) ? (int)Cu : CAND_CAP;
    const u64* cp = cand + (size_t)n * CAND_CAP;
    for (int i = threadIdx.x; i < C; i += 512) keys[i] = cp[i];
    __syncthreads();
    int t = threadIdx.x;
    int ci = bx * 256 + (t & 255);
    int half = t >> 8;                       // wave-uniform (waves 0-3: 0, waves 4-7: 1)
    unsigned int r = 0;
    u64 ki = 0;
    if (ci < C) {
        ki = keys[ci];
        int j = half;
        for (; j + 6 < C; j += 8) {          // 4 accumulations/iter, independent cmps
            r += (keys[j] > ki);
            r += (keys[j + 2] > ki);
            r += (keys[j + 4] > ki);
            r += (keys[j + 6] > ki);
        }
        for (; j < C; j += 2) r += (keys[j] > ki);
    }
    psum[t] = (unsigned short)r;
    __syncthreads();
    if (t < 256 && ci < C) {
        unsigned int rank = (unsigned int)psum[t] + (unsigned int)psum[t + 256];
        if (rank < K_TOP) {
            unsigned int u = (unsigned int)(ki >> 32);
            unsigned int m = ~((unsigned int)ki);
            float logit = unflip_key(u);
            int a = (int)(m % 3u);
            int hw = (int)(m / 3u);
            float4 anc = ((const float4*)anchors)[(size_t)n * M_ + m];
            size_t rb = ((size_t)n * 12 + a * 4) * HW_ + hw;
            float dx = breg[rb];
            float dy = breg[rb + (size_t)HW_];
            float dw = breg[rb + (size_t)2 * HW_];
            float dh = breg[rb + (size_t)3 * HW_];
            float score = 1.0f / (1.0f + expf(-logit));
            float w = anc.z - anc.x + 1.0f;
            float h = anc.w - anc.y + 1.0f;
            float cx = anc.x + 0.5f * w;
            float cy = anc.y + 0.5f * h;
            dw = fminf(dw, XCLIP);
            dh = fminf(dh, XCLIP);
            float pcx = dx * w + cx;
            float pcy = dy * h + cy;
            float pw = expf(dw) * w;
            float ph = expf(dh) * h;
            float x1 = pcx - 0.5f * pw;
            float y1 = pcy - 0.5f * ph;
            float x2 = pcx + 0.5f * pw - 1.0f;
            float y2 = pcy + 0.5f * ph - 1.0f;
            x1 = fminf(fmaxf(x1, 0.0f), 1332.0f);
            y1 = fminf(fmaxf(y1, 0.0f), 799.0f);
            x2 = fminf(fmaxf(x2, 0.0f), 1332.0f);
            y2 = fminf(fmaxf(y2, 0.0f), 799.0f);
            float ww = x2 - x1 + 1.0f;
            float hh = y2 - y1 + 1.0f;
            bool keep = (ww >= 0.0f) && (hh >= 0.0f);  // MIN_SIZE = 0
            int g = n * K_TOP + (int)rank;
            boxes[g] = make_float4(x1, y1, x2, y2);
            scores[g] = keep ? score : NEG_;
            areas[g] = ww * hh;
        }
    }
}

// ---------------- K5: dense adjacency bitmask: adj[n][i][w] bit b = IoU(i, 64w+b) > thr ----------------
// NOTE: IoU is computed with fully commutative float ops -> matrix is bitwise symmetric.
// k_resolve depends on this (uses rows as columns).
#define JT 512   // j's per block tile (8 u64 words)
#define RT 64    // rows per block tile
__global__ __launch_bounds__(256) void k_edges(const float4* __restrict__ boxes,
                                               const float* __restrict__ areas,
                                               u64* __restrict__ adj) {
    __shared__ float4 jb[JT];
    __shared__ float ja[JT];
    int n = blockIdx.z;
    int r0 = blockIdx.y * RT;
    int j0 = blockIdx.x * JT;
    for (int j = threadIdx.x; j < JT; j += 256) {
        int jj = j0 + j;
        if (jj < K_TOP) {
            jb[j] = boxes[(size_t)n * K_TOP + jj];
            ja[j] = areas[(size_t)n * K_TOP + jj];
        } else {
            jb[j] = make_float4(-1e8f, -1e8f, -1e8f, -1e8f);  // IoU vs anything = 0
            ja[j] = 0.0f;
        }
    }
    __syncthreads();
    int i = r0 + (threadIdx.x >> 2);       // 4 threads per row
    if (i >= K_TOP) return;
    float4 bi = boxes[(size_t)n * K_TOP + i];
    float ai = areas[(size_t)n * K_TOP + i];
    #pragma unroll
    for (int rep = 0; rep < 2; ++rep) {
        int wl = (threadIdx.x & 3) + rep * 4;  // word-in-tile 0..7
        u64 bits = 0;
        int base = wl * 64;
        #pragma unroll 8
        for (int b = 0; b < 64; ++b) {
            float4 bj = jb[base + b];
            float xx1 = fmaxf(bi.x, bj.x);
            float yy1 = fmaxf(bi.y, bj.y);
            float xx2 = fminf(bi.z, bj.z);
            float yy2 = fminf(bi.w, bj.w);
            float inter = fmaxf(xx2 - xx1 + 1.0f, 0.0f) * fmaxf(yy2 - yy1 + 1.0f, 0.0f);
            float iou = inter / (ai + ja[base + b] - inter);
            bits |= ((u64)(iou > NMS_THR_)) << b;
        }
        adj[((size_t)n * NPAD + i) * NW + (j0 >> 6) + wl] = bits;
    }
}

// ---------------- K6: wave-specialized greedy NMS; scalar-pipe serial select per chunk ----------------
// R10 lesson: ballot-Jacobi needed ~30-45 iterations/chunk on these dense graphs (~3.5K cyc of
// ballot->scalar->branch chains). Replaced with the EXACT 64-step greedy select run on the scalar
// pipe: v_readlane broadcasts column kk (independent of running state -> pipelines), the update is
// ~5 branchless scalar ops/step (~900 cyc total).
__global__ __launch_bounds__(256) void k_resolve(const float4* __restrict__ boxes,
                                                 const float* __restrict__ scores,
                                                 const u64* __restrict__ adj,
                                                 float* __restrict__ out) {
    __shared__ u64 ring[RING][64 * NW];     // 4 x 16 KiB = 64 KiB, CONTIGUOUS (DMA layout)
    __shared__ float sls[NPAD];             // 8 KiB
    __shared__ unsigned char alive[NPAD];   // 2 KiB (indices >= K_TOP stay 0)
    __shared__ int list[64];                // alive indices of current chunk (resolver-wave private)
    __shared__ int ready[RING];             // slot s holds chunk c when ready[s]==c+1
    __shared__ int progress;                // # chunks fully resolved
    __shared__ unsigned int scanbuf[256];
    int n = blockIdx.x;
    int tid = threadIdx.x;
    int wave = tid >> 6, lane = tid & 63;
    const u64* ab = adj + (size_t)n * NPAD * NW;

    for (int i = tid; i < NPAD; i += 256) {
        sls[i] = (i < K_TOP) ? scores[(size_t)n * K_TOP + i] : NEG_;
        alive[i] = 0;
    }
    if (tid < RING) ready[tid] = 0;
    if (tid == 0) progress = 0;
    __syncthreads();  // init visible to all waves (the ONLY barrier before the epilogue)

    if (wave == 0) {
        // ---- resolver ----
        u64 supreg = 0;  // lane w (w<32) holds suppressed-mask word w
        for (int c = 0; c < NCHUNK; ++c) {
            int slot = c & (RING - 1);
            while (__hip_atomic_load(&ready[slot], __ATOMIC_ACQUIRE,
                                     __HIP_MEMORY_SCOPE_WORKGROUP) != c + 1)
                __builtin_amdgcn_s_sleep(1);
            int k = lane;
            int gi = c * 64 + k;
            // symmetric adjacency: row gi word c == column k of the diag block
            u64 colk = ring[slot][k * NW + c];
            unsigned int clo = (unsigned int)colk, chi = (unsigned int)(colk >> 32);
            // sup word c via readlane (supreg lane c, c<32)
            unsigned int slo = (unsigned int)__builtin_amdgcn_readlane((int)(unsigned int)supreg, c);
            unsigned int shi = (unsigned int)__builtin_amdgcn_readlane((int)(unsigned int)(supreg >> 32), c);
            u64 supc = ((u64)shi << 32) | slo;
            u64 invmask = __ballot(sls[gi] <= VALID_THR_);
            u64 dead = supc | invmask;      // wave-uniform
            // exact greedy select, 64 scalar steps (readlanes independent -> pipeline)
            u64 aliveM = 0;
            #pragma unroll 8
            for (int kk = 0; kk < 64; ++kk) {
                u64 ck = ((u64)(unsigned int)__builtin_amdgcn_readlane((int)chi, kk) << 32)
                       | (unsigned int)__builtin_amdgcn_readlane((int)clo, kk);
                u64 bit = 1ull << kk;
                u64 sel = (dead & bit) ? 0ull : ~0ull;       // branchless cselect
                aliveM |= bit & sel;
                dead |= ck & sel & ~((2ull << kk) - 1ull);   // suppress only j > kk
            }
            alive[gi] = (unsigned char)((aliveM >> k) & 1ull);
            u64 below = (k == 0) ? 0ull : ((1ull << k) - 1ull);
            if ((aliveM >> k) & 1ull) list[__popcll(aliveM & below)] = k;
            int nal = (int)__popcll(aliveM);
            // sup-OR inside resolver wave: lane = half*32 + w
            int w = lane & 31, half = lane >> 5;
            u64 acc = 0;
            for (int i = half; i < nal; i += 2)
                acc |= ring[slot][list[i] * NW + w];
            acc |= __shfl_down(acc, 32);    // fold half 1 into half 0
            if (lane < 32) supreg |= acc;
            if (lane == 0)
                __hip_atomic_store(&progress, c + 1, __ATOMIC_RELEASE,
                                   __HIP_MEMORY_SCOPE_WORKGROUP);
        }
    } else {
        // ---- prefetchers: wave v handles chunks v-1, v+2, v+5, ... ----
        for (int c = wave - 1; c < NCHUNK; c += 3) {
            int slot = c & (RING - 1);
            // slot free once chunk c-4 consumed: progress >= c-3
            while (__hip_atomic_load(&progress, __ATOMIC_ACQUIRE,
                                     __HIP_MEMORY_SCOPE_WORKGROUP) < c - 3)
                __builtin_amdgcn_s_sleep(1);
            const u64* src = ab + (size_t)c * 64 * NW + lane * 2;  // 16 B per lane
            u64* dst = &ring[slot][0];
            #pragma unroll
            for (int it = 0; it < 16; ++it)   // 16 x 1 KiB DMA, back-to-back, no VGPR round-trip
                gload_lds16(src + (size_t)it * 128, dst + it * 128);
            __builtin_amdgcn_s_waitcnt(0);    // drain this wave's DMA (vmcnt) before publishing
            if (lane == 0)
                __hip_atomic_store(&ready[slot], c + 1, __ATOMIC_RELEASE,
                                   __HIP_MEMORY_SCOPE_WORKGROUP);
        }
    }
    __syncthreads();

    // --- order-preserving compaction of survivors -> output rows ---
    // i0 covers [0,2048): all arrays are NPAD-sized and alive[>=K_TOP]==0 (R3 lesson).
    int i0 = tid * 8;
    unsigned int c2 = 0;
    for (int i = i0; i < i0 + 8; ++i) c2 += alive[i];
    scanbuf[tid] = c2;
    __syncthreads();
    for (int off = 1; off < 256; off <<= 1) {
        unsigned int v = scanbuf[tid];
        unsigned int addv = (tid >= off) ? scanbuf[tid - off] : 0u;
        __syncthreads();
        scanbuf[tid] = v + addv;
        __syncthreads();
    }
    unsigned int r = scanbuf[tid] - c2;
    unsigned int total = scanbuf[255];
    float* op = out + (size_t)n * POST_N * 5;
    const float4* bb = boxes + (size_t)n * K_TOP;
    for (int i = i0; i < i0 + 8; ++i) {
        if (alive[i]) {
            if (r < POST_N) {
                float4 b = bb[i];
                op[r * 5 + 0] = b.x;
                op[r * 5 + 1] = b.y;
                op[r * 5 + 2] = b.z;
                op[r * 5 + 3] = b.w;
                op[r * 5 + 4] = sls[i];
            }
            r++;
        }
    }
    unsigned int S = (total > POST_N) ? POST_N : total;
    for (unsigned int q = S + tid; q < POST_N; q += 256) {
        op[q * 5 + 0] = 0.0f;
        op[q * 5 + 1] = 0.0f;
        op[q * 5 + 2] = 0.0f;
        op[q * 5 + 3] = 0.0f;
        op[q * 5 + 4] = 0.0f;
    }
}

extern "C" void kernel_launch(void* const* d_in, const int* in_sizes, int n_in,
                              void* d_out, int out_size, void* d_ws, size_t ws_size,
                              hipStream_t stream) {
    const float* anchors = (const float*)d_in[0];
    const float* logits  = (const float*)d_in[1];
    const float* breg    = (const float*)d_in[2];
    float* out = (float*)d_out;
    char* ws = (char*)d_ws;

    // ws layout (bytes) — adj ALIASES ghist+cand (both dead before k_edges writes adj):
    // [0, 32)               cnt    : u32[8]              (zeroed each launch)
    // [64, 96)              thresh : u32[8]              (written by k_scan)
    // [128, 2097280)        ghist  : u16[8][HBLK=32][4096]   \ dead after k_scan / k_rank
    // [2097280, 2359424)    cand   : u64[8][4096]            /
    // [128, 4194432)        adj    : u64[8][2048][32]    (written by k_edges after k_rank)
    // [4194432, 4450432)    boxes  : float4[8][2000]
    // [4450432, 4514432)    scores : f32[8][2000]
    // [4514432, 4578432)    areas  : f32[8][2000]
    unsigned int* cnt     = (unsigned int*)(ws);
    unsigned int* thresh  = (unsigned int*)(ws + 64);
    unsigned short* ghist = (unsigned short*)(ws + 128);
    u64* cand             = (u64*)(ws + 2097280);
    u64* adj              = (u64*)(ws + 128);
    float4* boxes         = (float4*)(ws + 4194432);
    float* scores         = (float*)(ws + 4450432);
    float* areas          = (float*)(ws + 4514432);

    hipMemsetAsync(ws, 0, 96, stream);

    k_hist<<<dim3(HBLK, 8), 512, 0, stream>>>(logits, ghist);
    k_scan<<<8, 256, 0, stream>>>(ghist, thresh);
    k_compact<<<dim3(HBLK, 8), 512, 0, stream>>>(logits, thresh, cnt, cand);
    k_rank<<<dim3(16, 8), 512, 0, stream>>>(cand, cnt, anchors, breg, boxes, scores, areas);
    k_edges<<<dim3(NPAD / JT, NPAD / RT, 8), 256, 0, stream>>>(boxes, areas, adj);
    k_resolve<<<8, 256, 0, stream>>>(boxes, scores, adj, out);
}

// Round 12
// 241.102 us; speedup vs baseline: 1.4128x; 1.4128x over previous
//
#include <hip/hip_runtime.h>
#include <stdint.h>

#define N_BATCH 8
#define A_ 3
#define H_ 336
#define W_ 336
#define HW_ (H_*W_)        // 112896
#define M_ (A_*HW_)        // 338688
#define K_TOP 2000
#define POST_N 1000
#define NMS_THR_ 0.7f
#define NEG_ (-1e9f)
#define VALID_THR_ (-5e8f)
#define CAND_CAP 4096
#define NBINS 4096
#define BIN_SHIFT 20       // top 12 bits: sign+exp+3 mantissa
#define HBLK 32            // histogram/compact blocks per batch (256 blocks total)
#define SEG_ (M_/HBLK)     // 10584
#define XCLIP 4.135166556742356f  // log(1000/16)

#define NPAD 2048          // boxes padded to 32 chunks of 64
#define NW 32              // u64 words per adjacency row (ring UNPADDED: global_load_lds needs contiguity)
#define NCHUNK 32
#define RING 4             // ring slots (chunk c -> slot c&3)

typedef unsigned long long u64;

__device__ __forceinline__ unsigned int flip_key(float x) {
    unsigned int u = __float_as_uint(x);
    return (u & 0x80000000u) ? ~u : (u | 0x80000000u);
}
__device__ __forceinline__ float unflip_key(unsigned int k) {
    unsigned int u = (k & 0x80000000u) ? (k & 0x7fffffffu) : ~k;
    return __uint_as_float(u);
}

// Direct global->LDS DMA, 16 B/lane, no VGPR round-trip.
__device__ __forceinline__ void gload_lds16(const u64* g, u64* l) {
    __builtin_amdgcn_global_load_lds(
        (const __attribute__((address_space(1))) unsigned int*)(const void*)g,
        (__attribute__((address_space(3))) unsigned int*)(void*)l,
        16, 0, 0);
}

// ---------------- K1: per-block LDS histogram -> private u16 sub-hist (no global atomics) ----------------
__global__ __launch_bounds__(512) void k_hist(const float* __restrict__ logits,
                                              unsigned short* __restrict__ ghist) {
    __shared__ unsigned int h[NBINS];  // 16 KiB
    int n = blockIdx.y, b = blockIdx.x;
    for (int i = threadIdx.x; i < NBINS; i += 512) h[i] = 0;
    __syncthreads();
    const float4* lp = (const float4*)(logits + (size_t)n * M_ + (size_t)b * SEG_);
    const int nq = SEG_ / 4;                 // 2646
    for (int q = threadIdx.x; q < nq; q += 512) {
        float4 v = lp[q];
        atomicAdd(&h[flip_key(v.x) >> BIN_SHIFT], 1u);
        atomicAdd(&h[flip_key(v.y) >> BIN_SHIFT], 1u);
        atomicAdd(&h[flip_key(v.z) >> BIN_SHIFT], 1u);
        atomicAdd(&h[flip_key(v.w) >> BIN_SHIFT], 1u);
    }
    __syncthreads();
    unsigned short* gp = ghist + ((size_t)n * HBLK + b) * NBINS;
    for (int i = threadIdx.x; i < NBINS; i += 512) gp[i] = (unsigned short)h[i];
}

// ---------------- K1b: sum sub-hists, find threshold bin B per batch ----------------
__global__ __launch_bounds__(256) void k_scan(const unsigned short* __restrict__ ghist,
                                              unsigned int* __restrict__ thresh) {
    int n = blockIdx.x;
    int t = threadIdx.x;
    __shared__ unsigned int binsum[NBINS];
    __shared__ unsigned int part[256];
    __shared__ unsigned int scanb[256];
    const unsigned short* base = ghist + (size_t)n * HBLK * NBINS;
    for (int i = t; i < NBINS; i += 256) {
        unsigned int s = 0;
        #pragma unroll 8
        for (int b = 0; b < HBLK; ++b) s += base[(size_t)b * NBINS + i];
        binsum[i] = s;
    }
    __syncthreads();
    // chunk t covers bins [NBINS-16*(t+1), NBINS-16*t) — descending chunks
    int hi = NBINS - 16 * t;
    int lo = hi - 16;
    unsigned int s = 0;
    for (int b = lo; b < hi; ++b) s += binsum[b];
    part[t] = s;
    scanb[t] = s;
    __syncthreads();
    for (int off = 1; off < 256; off <<= 1) {
        unsigned int v = scanb[t];
        unsigned int addv = (t >= off) ? scanb[t - off] : 0u;
        __syncthreads();
        scanb[t] = v + addv;
        __syncthreads();
    }
    unsigned int incl = scanb[t];
    unsigned int prefix = incl - part[t];
    if (prefix < K_TOP && incl >= K_TOP) {
        unsigned int acc = prefix;
        for (int b = hi - 1; b >= lo; --b) {
            unsigned int c = binsum[b];
            if (acc + c >= K_TOP) {
                thresh[n] = (unsigned int)b;
                break;
            }
            acc += c;
        }
    }
}

// ---------------- K2: compact candidates via LDS buffer + 1 global atomic per block ----------------
__global__ __launch_bounds__(512) void k_compact(const float* __restrict__ logits,
                                                 const unsigned int* __restrict__ thresh,
                                                 unsigned int* __restrict__ cnt,
                                                 u64* __restrict__ cand) {
    __shared__ u64 buf[CAND_CAP];  // 32 KiB
    __shared__ unsigned int lcnt;
    __shared__ unsigned int gbase;
    int n = blockIdx.y, b = blockIdx.x;
    unsigned int B = thresh[n];
    if (threadIdx.x == 0) lcnt = 0;
    __syncthreads();
    const int qbase = b * SEG_;
    const float4* lp = (const float4*)(logits + (size_t)n * M_ + (size_t)qbase);
    const int nq = SEG_ / 4;
    for (int q = threadIdx.x; q < nq; q += 512) {
        float4 v = lp[q];
        float vv[4] = {v.x, v.y, v.z, v.w};
        #pragma unroll
        for (int e = 0; e < 4; ++e) {
            unsigned int u = flip_key(vv[e]);
            if ((u >> BIN_SHIFT) >= B) {
                int qq = qbase + q * 4 + e;
                int a = qq / HW_;
                int hw = qq - a * HW_;
                unsigned int m = (unsigned int)(hw * A_ + a);  // score-order index
                unsigned int pos = atomicAdd(&lcnt, 1u);
                if (pos < CAND_CAP)
                    buf[pos] = ((u64)u << 32) | (unsigned int)(~m);
            }
        }
    }
    __syncthreads();
    unsigned int L = (lcnt < CAND_CAP) ? lcnt : CAND_CAP;
    if (threadIdx.x == 0) gbase = atomicAdd(&cnt[n], L);
    __syncthreads();
    u64* cp = cand + (size_t)n * CAND_CAP;
    for (unsigned int i = threadIdx.x; i < L; i += 512) {
        unsigned int pos = gbase + i;
        if (pos < CAND_CAP) cp[pos] = buf[i];
    }
}

// ---------------- K3: rank-by-counting (replaces bitonic sort) + fused decode ----------------
// Keys are unique -> rank(i) = #{j: key_j > key_i} is a permutation; rank < K_TOP
// candidates ARE the sorted top-2000 (desc, ties by smaller m — matches lax.top_k).
__global__ __launch_bounds__(512) void k_rank(const u64* __restrict__ cand,
                                              const unsigned int* __restrict__ cnt,
                                              const float* __restrict__ anchors,
                                              const float* __restrict__ breg,
                                              float4* __restrict__ boxes,
                                              float* __restrict__ scores,
                                              float* __restrict__ areas) {
    __shared__ u64 keys[CAND_CAP];          // 32 KiB
    __shared__ unsigned short psum[512];
    int n = blockIdx.y;
    int bx = blockIdx.x;
    unsigned int Cu = cnt[n];
    int C = (Cu < CAND_CAP) ? (int)Cu : CAND_CAP;
    const u64* cp = cand + (size_t)n * CAND_CAP;
    for (int i = threadIdx.x; i < C; i += 512) keys[i] = cp[i];
    __syncthreads();
    int t = threadIdx.x;
    int ci = bx * 256 + (t & 255);
    int half = t >> 8;                       // wave-uniform (waves 0-3: 0, waves 4-7: 1)
    unsigned int r = 0;
    u64 ki = 0;
    if (ci < C) {
        ki = keys[ci];
        int j = half;
        for (; j + 6 < C; j += 8) {          // 4 accumulations/iter, independent cmps
            r += (keys[j] > ki);
            r += (keys[j + 2] > ki);
            r += (keys[j + 4] > ki);
            r += (keys[j + 6] > ki);
        }
        for (; j < C; j += 2) r += (keys[j] > ki);
    }
    psum[t] = (unsigned short)r;
    __syncthreads();
    if (t < 256 && ci < C) {
        unsigned int rank = (unsigned int)psum[t] + (unsigned int)psum[t + 256];
        if (rank < K_TOP) {
            unsigned int u = (unsigned int)(ki >> 32);
            unsigned int m = ~((unsigned int)ki);
            float logit = unflip_key(u);
            int a = (int)(m % 3u);
            int hw = (int)(m / 3u);
            float4 anc = ((const float4*)anchors)[(size_t)n * M_ + m];
            size_t rb = ((size_t)n * 12 + a * 4) * HW_ + hw;
            float dx = breg[rb];
            float dy = breg[rb + (size_t)HW_];
            float dw = breg[rb + (size_t)2 * HW_];
            float dh = breg[rb + (size_t)3 * HW_];
            float score = 1.0f / (1.0f + expf(-logit));
            float w = anc.z - anc.x + 1.0f;
            float h = anc.w - anc.y + 1.0f;
            float cx = anc.x + 0.5f * w;
            float cy = anc.y + 0.5f * h;
            dw = fminf(dw, XCLIP);
            dh = fminf(dh, XCLIP);
            float pcx = dx * w + cx;
            float pcy = dy * h + cy;
            float pw = expf(dw) * w;
            float ph = expf(dh) * h;
            float x1 = pcx - 0.5f * pw;
            float y1 = pcy - 0.5f * ph;
            float x2 = pcx + 0.5f * pw - 1.0f;
            float y2 = pcy + 0.5f * ph - 1.0f;
            x1 = fminf(fmaxf(x1, 0.0f), 1332.0f);
            y1 = fminf(fmaxf(y1, 0.0f), 799.0f);
            x2 = fminf(fmaxf(x2, 0.0f), 1332.0f);
            y2 = fminf(fmaxf(y2, 0.0f), 799.0f);
            float ww = x2 - x1 + 1.0f;
            float hh = y2 - y1 + 1.0f;
            bool keep = (ww >= 0.0f) && (hh >= 0.0f);  // MIN_SIZE = 0
            int g = n * K_TOP + (int)rank;
            boxes[g] = make_float4(x1, y1, x2, y2);
            scores[g] = keep ? score : NEG_;
            areas[g] = ww * hh;
        }
    }
}

// ---------------- K5: dense adjacency bitmask: adj[n][i][w] bit b = IoU(i, 64w+b) > thr ----------------
// NOTE: IoU is computed with fully commutative float ops -> matrix is bitwise symmetric.
// k_resolve depends on this (uses rows as columns).
#define JT 512   // j's per block tile (8 u64 words)
#define RT 64    // rows per block tile
__global__ __launch_bounds__(256) void k_edges(const float4* __restrict__ boxes,
                                               const float* __restrict__ areas,
                                               u64* __restrict__ adj) {
    __shared__ float4 jb[JT];
    __shared__ float ja[JT];
    int n = blockIdx.z;
    int r0 = blockIdx.y * RT;
    int j0 = blockIdx.x * JT;
    for (int j = threadIdx.x; j < JT; j += 256) {
        int jj = j0 + j;
        if (jj < K_TOP) {
            jb[j] = boxes[(size_t)n * K_TOP + jj];
            ja[j] = areas[(size_t)n * K_TOP + jj];
        } else {
            jb[j] = make_float4(-1e8f, -1e8f, -1e8f, -1e8f);  // IoU vs anything = 0
            ja[j] = 0.0f;
        }
    }
    __syncthreads();
    int i = r0 + (threadIdx.x >> 2);       // 4 threads per row
    if (i >= K_TOP) return;
    float4 bi = boxes[(size_t)n * K_TOP + i];
    float ai = areas[(size_t)n * K_TOP + i];
    #pragma unroll
    for (int rep = 0; rep < 2; ++rep) {
        int wl = (threadIdx.x & 3) + rep * 4;  // word-in-tile 0..7
        u64 bits = 0;
        int base = wl * 64;
        #pragma unroll 8
        for (int b = 0; b < 64; ++b) {
            float4 bj = jb[base + b];
            float xx1 = fmaxf(bi.x, bj.x);
            float yy1 = fmaxf(bi.y, bj.y);
            float xx2 = fminf(bi.z, bj.z);
            float yy2 = fminf(bi.w, bj.w);
            float inter = fmaxf(xx2 - xx1 + 1.0f, 0.0f) * fmaxf(yy2 - yy1 + 1.0f, 0.0f);
            float iou = inter / (ai + ja[base + b] - inter);
            bits |= ((u64)(iou > NMS_THR_)) << b;
        }
        adj[((size_t)n * NPAD + i) * NW + (j0 >> 6) + wl] = bits;
    }
}

// ---------------- K6: wave-specialized greedy NMS (ballot-Jacobi, REVERTED from R10 scalar) ----------------
// R11 lesson: 64-step scalar readlane chain = 148 µs (worse than Jacobi's 78). Reverted.
// NEW: early exit — greedy is one-directional, so once cumulative alive >= POST_N the
// remaining chunks cannot affect the output (exactly min(survivors,1000) rows are emitted).
__global__ __launch_bounds__(256) void k_resolve(const float4* __restrict__ boxes,
                                                 const float* __restrict__ scores,
                                                 const u64* __restrict__ adj,
                                                 float* __restrict__ out) {
    __shared__ u64 ring[RING][64 * NW];     // 4 x 16 KiB = 64 KiB, CONTIGUOUS (DMA layout)
    __shared__ float sls[NPAD];             // 8 KiB
    __shared__ unsigned char alive[NPAD];   // 2 KiB (indices >= K_TOP stay 0)
    __shared__ int list[64];                // alive indices of current chunk (resolver-wave private)
    __shared__ int ready[RING];             // slot s holds chunk c when ready[s]==c+1
    __shared__ int progress;                // # chunks fully resolved
    __shared__ unsigned int scanbuf[256];
    int n = blockIdx.x;
    int tid = threadIdx.x;
    int wave = tid >> 6, lane = tid & 63;
    const u64* ab = adj + (size_t)n * NPAD * NW;

    for (int i = tid; i < NPAD; i += 256) {
        sls[i] = (i < K_TOP) ? scores[(size_t)n * K_TOP + i] : NEG_;
        alive[i] = 0;
    }
    if (tid < RING) ready[tid] = 0;
    if (tid == 0) progress = 0;
    __syncthreads();  // init visible to all waves (the ONLY barrier before the epilogue)

    if (wave == 0) {
        // ---- resolver ----
        u64 supreg = 0;  // lane w (w<32) holds suppressed-mask word w
        int survTot = 0;
        for (int c = 0; c < NCHUNK; ++c) {
            int slot = c & (RING - 1);
            while (__hip_atomic_load(&ready[slot], __ATOMIC_ACQUIRE,
                                     __HIP_MEMORY_SCOPE_WORKGROUP) != c + 1)
                __builtin_amdgcn_s_sleep(1);
            int k = lane;
            int gi = c * 64 + k;
            // symmetric adjacency: row gi word c == column k of the diag block
            u64 colk = ring[slot][k * NW + c];
            u64 supc = __shfl(supreg, c, 64);
            bool validk = (sls[gi] > VALID_THR_) && !((supc >> k) & 1ull);
            u64 below = (k == 0) ? 0ull : ((1ull << k) - 1ull);
            u64 rel = colk & below;
            // ballot-Jacobi: well-founded in k -> unique fixed point == greedy result
            bool a = validk;
            u64 am = __ballot(a);
            while (true) {
                bool anew = validk && ((am & rel) == 0ull);
                u64 am2 = __ballot(anew);
                if (am2 == am) { a = anew; break; }
                am = am2;
            }
            alive[gi] = a ? 1 : 0;
            if (a) list[__popcll(am & below)] = k;
            int nal = (int)__popcll(am);
            survTot += nal;
            if (survTot >= POST_N) {
                // later boxes can't affect the first POST_N output rows -> done.
                if (lane == 0)
                    __hip_atomic_store(&progress, NCHUNK, __ATOMIC_RELEASE,
                                       __HIP_MEMORY_SCOPE_WORKGROUP);
                break;
            }
            // sup-OR inside resolver wave: lane = half*32 + w
            int w = lane & 31, half = lane >> 5;
            u64 acc = 0;
            for (int i = half; i < nal; i += 2)
                acc |= ring[slot][list[i] * NW + w];
            acc |= __shfl_down(acc, 32);    // fold half 1 into half 0
            if (lane < 32) supreg |= acc;
            if (lane == 0)
                __hip_atomic_store(&progress, c + 1, __ATOMIC_RELEASE,
                                   __HIP_MEMORY_SCOPE_WORKGROUP);
        }
    } else {
        // ---- prefetchers: wave v handles chunks v-1, v+2, v+5, ... ----
        // On resolver early-exit, progress jumps to NCHUNK: no prefetcher ever blocks,
        // remaining DMA is harmless (ring unused past exit).
        for (int c = wave - 1; c < NCHUNK; c += 3) {
            int slot = c & (RING - 1);
            // slot free once chunk c-4 consumed: progress >= c-3
            while (__hip_atomic_load(&progress, __ATOMIC_ACQUIRE,
                                     __HIP_MEMORY_SCOPE_WORKGROUP) < c - 3)
                __builtin_amdgcn_s_sleep(1);
            const u64* src = ab + (size_t)c * 64 * NW + lane * 2;  // 16 B per lane
            u64* dst = &ring[slot][0];
            #pragma unroll
            for (int it = 0; it < 16; ++it)   // 16 x 1 KiB DMA, back-to-back, no VGPR round-trip
                gload_lds16(src + (size_t)it * 128, dst + it * 128);
            __builtin_amdgcn_s_waitcnt(0);    // drain this wave's DMA (vmcnt) before publishing
            if (lane == 0)
                __hip_atomic_store(&ready[slot], c + 1, __ATOMIC_RELEASE,
                                   __HIP_MEMORY_SCOPE_WORKGROUP);
        }
    }
    __syncthreads();

    // --- order-preserving compaction of survivors -> output rows ---
    // i0 covers [0,2048): all arrays are NPAD-sized and alive[>=K_TOP]==0 (R3 lesson).
    int i0 = tid * 8;
    unsigned int c2 = 0;
    for (int i = i0; i < i0 + 8; ++i) c2 += alive[i];
    scanbuf[tid] = c2;
    __syncthreads();
    for (int off = 1; off < 256; off <<= 1) {
        unsigned int v = scanbuf[tid];
        unsigned int addv = (tid >= off) ? scanbuf[tid - off] : 0u;
        __syncthreads();
        scanbuf[tid] = v + addv;
        __syncthreads();
    }
    unsigned int r = scanbuf[tid] - c2;
    unsigned int total = scanbuf[255];
    float* op = out + (size_t)n * POST_N * 5;
    const float4* bb = boxes + (size_t)n * K_TOP;
    for (int i = i0; i < i0 + 8; ++i) {
        if (alive[i]) {
            if (r < POST_N) {
                float4 b = bb[i];
                op[r * 5 + 0] = b.x;
                op[r * 5 + 1] = b.y;
                op[r * 5 + 2] = b.z;
                op[r * 5 + 3] = b.w;
                op[r * 5 + 4] = sls[i];
            }
            r++;
        }
    }
    unsigned int S = (total > POST_N) ? POST_N : total;
    for (unsigned int q = S + tid; q < POST_N; q += 256) {
        op[q * 5 + 0] = 0.0f;
        op[q * 5 + 1] = 0.0f;
        op[q * 5 + 2] = 0.0f;
        op[q * 5 + 3] = 0.0f;
        op[q * 5 + 4] = 0.0f;
    }
}

extern "C" void kernel_launch(void* const* d_in, const int* in_sizes, int n_in,
                              void* d_out, int out_size, void* d_ws, size_t ws_size,
                              hipStream_t stream) {
    const float* anchors = (const float*)d_in[0];
    const float* logits  = (const float*)d_in[1];
    const float* breg    = (const float*)d_in[2];
    float* out = (float*)d_out;
    char* ws = (char*)d_ws;

    // ws layout (bytes) — adj ALIASES ghist+cand (both dead before k_edges writes adj):
    // [0, 32)               cnt    : u32[8]              (zeroed each launch)
    // [64, 96)              thresh : u32[8]              (written by k_scan)
    // [128, 2097280)        ghist  : u16[8][HBLK=32][4096]   \ dead after k_scan / k_rank
    // [2097280, 2359424)    cand   : u64[8][4096]            /
    // [128, 4194432)        adj    : u64[8][2048][32]    (written by k_edges after k_rank)
    // [4194432, 4450432)    boxes  : float4[8][2000]
    // [4450432, 4514432)    scores : f32[8][2000]
    // [4514432, 4578432)    areas  : f32[8][2000]
    unsigned int* cnt     = (unsigned int*)(ws);
    unsigned int* thresh  = (unsigned int*)(ws + 64);
    unsigned short* ghist = (unsigned short*)(ws + 128);
    u64* cand             = (u64*)(ws + 2097280);
    u64* adj              = (u64*)(ws + 128);
    float4* boxes         = (float4*)(ws + 4194432);
    float* scores         = (float*)(ws + 4450432);
    float* areas          = (float*)(ws + 4514432);

    hipMemsetAsync(ws, 0, 96, stream);

    k_hist<<<dim3(HBLK, 8), 512, 0, stream>>>(logits, ghist);
    k_scan<<<8, 256, 0, stream>>>(ghist, thresh);
    k_compact<<<dim3(HBLK, 8), 512, 0, stream>>>(logits, thresh, cnt, cand);
    k_rank<<<dim3(16, 8), 512, 0, stream>>>(cand, cnt, anchors, breg, boxes, scores, areas);
    k_edges<<<dim3(NPAD / JT, NPAD / RT, 8), 256, 0, stream>>>(boxes, areas, adj);
    k_resolve<<<8, 256, 0, stream>>>(boxes, scores, adj, out);
}

// Round 13
// 223.225 us; speedup vs baseline: 1.5260x; 1.0801x over previous
//
#include <hip/hip_runtime.h>
#include <stdint.h>

#define N_BATCH 8
#define A_ 3
#define H_ 336
#define W_ 336
#define HW_ (H_*W_)        // 112896
#define M_ (A_*HW_)        // 338688
#define K_TOP 2000
#define POST_N 1000
#define NMS_THR_ 0.7f
#define NEG_ (-1e9f)
#define VALID_THR_ (-5e8f)
#define CAND_CAP 4096
#define NBINS 4096
#define BIN_SHIFT 20       // top 12 bits: sign+exp+3 mantissa
#define HBLK 32            // histogram/compact blocks per batch (256 blocks total)
#define SEG_ (M_/HBLK)     // 10584
#define XCLIP 4.135166556742356f  // log(1000/16)

#define NPAD 2048          // boxes padded to 32 chunks of 64
#define NW 32              // u64 words per adjacency row (ring UNPADDED: global_load_lds needs contiguity)
#define NCHUNK 32
#define RING 4             // ring slots (chunk c -> slot c&3)

typedef unsigned long long u64;

__device__ __forceinline__ unsigned int flip_key(float x) {
    unsigned int u = __float_as_uint(x);
    return (u & 0x80000000u) ? ~u : (u | 0x80000000u);
}
__device__ __forceinline__ float unflip_key(unsigned int k) {
    unsigned int u = (k & 0x80000000u) ? (k & 0x7fffffffu) : ~k;
    return __uint_as_float(u);
}

// Direct global->LDS DMA, 16 B/lane, no VGPR round-trip.
__device__ __forceinline__ void gload_lds16(const u64* g, u64* l) {
    __builtin_amdgcn_global_load_lds(
        (const __attribute__((address_space(1))) unsigned int*)(const void*)g,
        (__attribute__((address_space(3))) unsigned int*)(void*)l,
        16, 0, 0);
}

// ---------------- K1: per-block LDS histogram -> private u16 sub-hist (no global atomics) ----------------
__global__ __launch_bounds__(512) void k_hist(const float* __restrict__ logits,
                                              unsigned short* __restrict__ ghist) {
    __shared__ unsigned int h[NBINS];  // 16 KiB
    int n = blockIdx.y, b = blockIdx.x;
    for (int i = threadIdx.x; i < NBINS; i += 512) h[i] = 0;
    __syncthreads();
    const float4* lp = (const float4*)(logits + (size_t)n * M_ + (size_t)b * SEG_);
    const int nq = SEG_ / 4;                 // 2646
    for (int q = threadIdx.x; q < nq; q += 512) {
        float4 v = lp[q];
        atomicAdd(&h[flip_key(v.x) >> BIN_SHIFT], 1u);
        atomicAdd(&h[flip_key(v.y) >> BIN_SHIFT], 1u);
        atomicAdd(&h[flip_key(v.z) >> BIN_SHIFT], 1u);
        atomicAdd(&h[flip_key(v.w) >> BIN_SHIFT], 1u);
    }
    __syncthreads();
    unsigned short* gp = ghist + ((size_t)n * HBLK + b) * NBINS;
    for (int i = threadIdx.x; i < NBINS; i += 512) gp[i] = (unsigned short)h[i];
}

// ---------------- K1b: sum sub-hists, find threshold bin B per batch ----------------
__global__ __launch_bounds__(256) void k_scan(const unsigned short* __restrict__ ghist,
                                              unsigned int* __restrict__ thresh) {
    int n = blockIdx.x;
    int t = threadIdx.x;
    __shared__ unsigned int binsum[NBINS];
    __shared__ unsigned int part[256];
    __shared__ unsigned int scanb[256];
    const unsigned short* base = ghist + (size_t)n * HBLK * NBINS;
    for (int i = t; i < NBINS; i += 256) {
        unsigned int s = 0;
        #pragma unroll 8
        for (int b = 0; b < HBLK; ++b) s += base[(size_t)b * NBINS + i];
        binsum[i] = s;
    }
    __syncthreads();
    // chunk t covers bins [NBINS-16*(t+1), NBINS-16*t) — descending chunks
    int hi = NBINS - 16 * t;
    int lo = hi - 16;
    unsigned int s = 0;
    for (int b = lo; b < hi; ++b) s += binsum[b];
    part[t] = s;
    scanb[t] = s;
    __syncthreads();
    for (int off = 1; off < 256; off <<= 1) {
        unsigned int v = scanb[t];
        unsigned int addv = (t >= off) ? scanb[t - off] : 0u;
        __syncthreads();
        scanb[t] = v + addv;
        __syncthreads();
    }
    unsigned int incl = scanb[t];
    unsigned int prefix = incl - part[t];
    if (prefix < K_TOP && incl >= K_TOP) {
        unsigned int acc = prefix;
        for (int b = hi - 1; b >= lo; --b) {
            unsigned int c = binsum[b];
            if (acc + c >= K_TOP) {
                thresh[n] = (unsigned int)b;
                break;
            }
            acc += c;
        }
    }
}

// ---------------- K2: compact candidates via LDS buffer + 1 global atomic per block ----------------
__global__ __launch_bounds__(512) void k_compact(const float* __restrict__ logits,
                                                 const unsigned int* __restrict__ thresh,
                                                 unsigned int* __restrict__ cnt,
                                                 u64* __restrict__ cand) {
    __shared__ u64 buf[CAND_CAP];  // 32 KiB
    __shared__ unsigned int lcnt;
    __shared__ unsigned int gbase;
    int n = blockIdx.y, b = blockIdx.x;
    unsigned int B = thresh[n];
    if (threadIdx.x == 0) lcnt = 0;
    __syncthreads();
    const int qbase = b * SEG_;
    const float4* lp = (const float4*)(logits + (size_t)n * M_ + (size_t)qbase);
    const int nq = SEG_ / 4;
    for (int q = threadIdx.x; q < nq; q += 512) {
        float4 v = lp[q];
        float vv[4] = {v.x, v.y, v.z, v.w};
        #pragma unroll
        for (int e = 0; e < 4; ++e) {
            unsigned int u = flip_key(vv[e]);
            if ((u >> BIN_SHIFT) >= B) {
                int qq = qbase + q * 4 + e;
                int a = qq / HW_;
                int hw = qq - a * HW_;
                unsigned int m = (unsigned int)(hw * A_ + a);  // score-order index
                unsigned int pos = atomicAdd(&lcnt, 1u);
                if (pos < CAND_CAP)
                    buf[pos] = ((u64)u << 32) | (unsigned int)(~m);
            }
        }
    }
    __syncthreads();
    unsigned int L = (lcnt < CAND_CAP) ? lcnt : CAND_CAP;
    if (threadIdx.x == 0) gbase = atomicAdd(&cnt[n], L);
    __syncthreads();
    u64* cp = cand + (size_t)n * CAND_CAP;
    for (unsigned int i = threadIdx.x; i < L; i += 512) {
        unsigned int pos = gbase + i;
        if (pos < CAND_CAP) cp[pos] = buf[i];
    }
}

// ---------------- K3: rank-by-counting (replaces bitonic sort) + fused decode ----------------
// Keys are unique -> rank(i) = #{j: key_j > key_i} is a permutation; rank < K_TOP
// candidates ARE the sorted top-2000 (desc, ties by smaller m — matches lax.top_k).
__global__ __launch_bounds__(512) void k_rank(const u64* __restrict__ cand,
                                              const unsigned int* __restrict__ cnt,
                                              const float* __restrict__ anchors,
                                              const float* __restrict__ breg,
                                              float4* __restrict__ boxes,
                                              float* __restrict__ scores,
                                              float* __restrict__ areas) {
    __shared__ u64 keys[CAND_CAP];          // 32 KiB
    __shared__ unsigned short psum[512];
    int n = blockIdx.y;
    int bx = blockIdx.x;
    unsigned int Cu = cnt[n];
    int C = (Cu < CAND_CAP) ? (int)Cu : CAND_CAP;
    const u64* cp = cand + (size_t)n * CAND_CAP;
    for (int i = threadIdx.x; i < C; i += 512) keys[i] = cp[i];
    __syncthreads();
    int t = threadIdx.x;
    int ci = bx * 256 + (t & 255);
    int half = t >> 8;                       // wave-uniform (waves 0-3: 0, waves 4-7: 1)
    unsigned int r = 0;
    u64 ki = 0;
    if (ci < C) {
        ki = keys[ci];
        int j = half;
        for (; j + 6 < C; j += 8) {          // 4 accumulations/iter, independent cmps
            r += (keys[j] > ki);
            r += (keys[j + 2] > ki);
            r += (keys[j + 4] > ki);
            r += (keys[j + 6] > ki);
        }
        for (; j < C; j += 2) r += (keys[j] > ki);
    }
    psum[t] = (unsigned short)r;
    __syncthreads();
    if (t < 256 && ci < C) {
        unsigned int rank = (unsigned int)psum[t] + (unsigned int)psum[t + 256];
        if (rank < K_TOP) {
            unsigned int u = (unsigned int)(ki >> 32);
            unsigned int m = ~((unsigned int)ki);
            float logit = unflip_key(u);
            int a = (int)(m % 3u);
            int hw = (int)(m / 3u);
            float4 anc = ((const float4*)anchors)[(size_t)n * M_ + m];
            size_t rb = ((size_t)n * 12 + a * 4) * HW_ + hw;
            float dx = breg[rb];
            float dy = breg[rb + (size_t)HW_];
            float dw = breg[rb + (size_t)2 * HW_];
            float dh = breg[rb + (size_t)3 * HW_];
            float score = 1.0f / (1.0f + expf(-logit));
            float w = anc.z - anc.x + 1.0f;
            float h = anc.w - anc.y + 1.0f;
            float cx = anc.x + 0.5f * w;
            float cy = anc.y + 0.5f * h;
            dw = fminf(dw, XCLIP);
            dh = fminf(dh, XCLIP);
            float pcx = dx * w + cx;
            float pcy = dy * h + cy;
            float pw = expf(dw) * w;
            float ph = expf(dh) * h;
            float x1 = pcx - 0.5f * pw;
            float y1 = pcy - 0.5f * ph;
            float x2 = pcx + 0.5f * pw - 1.0f;
            float y2 = pcy + 0.5f * ph - 1.0f;
            x1 = fminf(fmaxf(x1, 0.0f), 1332.0f);
            y1 = fminf(fmaxf(y1, 0.0f), 799.0f);
            x2 = fminf(fmaxf(x2, 0.0f), 1332.0f);
            y2 = fminf(fmaxf(y2, 0.0f), 799.0f);
            float ww = x2 - x1 + 1.0f;
            float hh = y2 - y1 + 1.0f;
            bool keep = (ww >= 0.0f) && (hh >= 0.0f);  // MIN_SIZE = 0
            int g = n * K_TOP + (int)rank;
            boxes[g] = make_float4(x1, y1, x2, y2);
            scores[g] = keep ? score : NEG_;
            areas[g] = ww * hh;
        }
    }
}

// ---------------- K5: dense adjacency bitmask: adj[n][i][w] bit b = IoU(i, 64w+b) > thr ----------------
// NOTE: IoU is computed with fully commutative float ops -> matrix is bitwise symmetric.
// k_resolve depends on this (uses rows as columns).
#define JT 512   // j's per block tile (8 u64 words)
#define RT 64    // rows per block tile
__global__ __launch_bounds__(256) void k_edges(const float4* __restrict__ boxes,
                                               const float* __restrict__ areas,
                                               u64* __restrict__ adj) {
    __shared__ float4 jb[JT];
    __shared__ float ja[JT];
    int n = blockIdx.z;
    int r0 = blockIdx.y * RT;
    int j0 = blockIdx.x * JT;
    for (int j = threadIdx.x; j < JT; j += 256) {
        int jj = j0 + j;
        if (jj < K_TOP) {
            jb[j] = boxes[(size_t)n * K_TOP + jj];
            ja[j] = areas[(size_t)n * K_TOP + jj];
        } else {
            jb[j] = make_float4(-1e8f, -1e8f, -1e8f, -1e8f);  // IoU vs anything = 0
            ja[j] = 0.0f;
        }
    }
    __syncthreads();
    int i = r0 + (threadIdx.x >> 2);       // 4 threads per row
    if (i >= K_TOP) return;
    float4 bi = boxes[(size_t)n * K_TOP + i];
    float ai = areas[(size_t)n * K_TOP + i];
    #pragma unroll
    for (int rep = 0; rep < 2; ++rep) {
        int wl = (threadIdx.x & 3) + rep * 4;  // word-in-tile 0..7
        u64 bits = 0;
        int base = wl * 64;
        #pragma unroll 8
        for (int b = 0; b < 64; ++b) {
            float4 bj = jb[base + b];
            float xx1 = fmaxf(bi.x, bj.x);
            float yy1 = fmaxf(bi.y, bj.y);
            float xx2 = fminf(bi.z, bj.z);
            float yy2 = fminf(bi.w, bj.w);
            float inter = fmaxf(xx2 - xx1 + 1.0f, 0.0f) * fmaxf(yy2 - yy1 + 1.0f, 0.0f);
            float iou = inter / (ai + ja[base + b] - inter);
            bits |= ((u64)(iou > NMS_THR_)) << b;
        }
        adj[((size_t)n * NPAD + i) * NW + (j0 >> 6) + wl] = bits;
    }
}

// ---------------- K6: wave-specialized greedy NMS (ballot-Jacobi + early exit) ----------------
// R12 lesson: the 5.8K cyc/chunk floor was the sup-OR's dependent 2-hop LDS chain
// (list[i] read -> ring read, ~240 cyc x ~25 iters). Fix: iterate set bits of the
// register-uniform alive mask (ffsll, ~5 cyc) and issue 4 INDEPENDENT ds_reads per
// group before one waitcnt. OR is idempotent -> short groups pad by repeating k1.
__global__ __launch_bounds__(256) void k_resolve(const float4* __restrict__ boxes,
                                                 const float* __restrict__ scores,
                                                 const u64* __restrict__ adj,
                                                 float* __restrict__ out) {
    __shared__ u64 ring[RING][64 * NW];     // 4 x 16 KiB = 64 KiB, CONTIGUOUS (DMA layout)
    __shared__ float sls[NPAD];             // 8 KiB
    __shared__ unsigned char alive[NPAD];   // 2 KiB (indices >= K_TOP stay 0)
    __shared__ int ready[RING];             // slot s holds chunk c when ready[s]==c+1
    __shared__ int progress;                // # chunks fully resolved
    __shared__ unsigned int scanbuf[256];
    int n = blockIdx.x;
    int tid = threadIdx.x;
    int wave = tid >> 6, lane = tid & 63;
    const u64* ab = adj + (size_t)n * NPAD * NW;

    for (int i = tid; i < NPAD; i += 256) {
        sls[i] = (i < K_TOP) ? scores[(size_t)n * K_TOP + i] : NEG_;
        alive[i] = 0;
    }
    if (tid < RING) ready[tid] = 0;
    if (tid == 0) progress = 0;
    __syncthreads();  // init visible to all waves (the ONLY barrier before the epilogue)

    if (wave == 0) {
        // ---- resolver ----
        u64 supreg = 0;  // lane w (w<32) holds suppressed-mask word w
        int survTot = 0;
        for (int c = 0; c < NCHUNK; ++c) {
            int slot = c & (RING - 1);
            while (__hip_atomic_load(&ready[slot], __ATOMIC_ACQUIRE,
                                     __HIP_MEMORY_SCOPE_WORKGROUP) != c + 1)
                __builtin_amdgcn_s_sleep(1);
            int k = lane;
            int gi = c * 64 + k;
            // symmetric adjacency: row gi word c == column k of the diag block
            u64 colk = ring[slot][k * NW + c];
            u64 supc = __shfl(supreg, c, 64);
            bool validk = (sls[gi] > VALID_THR_) && !((supc >> k) & 1ull);
            u64 below = (k == 0) ? 0ull : ((1ull << k) - 1ull);
            u64 rel = colk & below;
            // ballot-Jacobi: well-founded in k -> unique fixed point == greedy result
            bool a = validk;
            u64 am = __ballot(a);
            while (true) {
                bool anew = validk && ((am & rel) == 0ull);
                u64 am2 = __ballot(anew);
                if (am2 == am) { a = anew; break; }
                am = am2;
            }
            alive[gi] = a ? 1 : 0;
            int nal = (int)__popcll(am);
            survTot += nal;
            if (survTot >= POST_N) {
                // later boxes can't affect the first POST_N output rows -> done.
                if (lane == 0)
                    __hip_atomic_store(&progress, NCHUNK, __ATOMIC_RELEASE,
                                       __HIP_MEMORY_SCOPE_WORKGROUP);
                break;
            }
            // sup-OR: iterate set bits of am (uniform in registers), parity-split across
            // wave halves, 4 independent ds_reads per group (single waitcnt, pipelined).
            int w = lane & 31, half = lane >> 5;
            u64 acc = 0;
            u64 m = am & (half ? 0xAAAAAAAAAAAAAAAAull : 0x5555555555555555ull);
            while (m) {
                int k1 = __ffsll((unsigned long long)m) - 1; m &= m - 1;
                int k2 = k1, k3 = k1, k4 = k1;
                if (m) { k2 = __ffsll((unsigned long long)m) - 1; m &= m - 1; }
                if (m) { k3 = __ffsll((unsigned long long)m) - 1; m &= m - 1; }
                if (m) { k4 = __ffsll((unsigned long long)m) - 1; m &= m - 1; }
                u64 r1 = ring[slot][k1 * NW + w];
                u64 r2 = ring[slot][k2 * NW + w];
                u64 r3 = ring[slot][k3 * NW + w];
                u64 r4 = ring[slot][k4 * NW + w];
                acc |= r1 | r2 | r3 | r4;   // idempotent: duplicate pads harmless
            }
            acc |= __shfl_down(acc, 32);    // fold half 1 into half 0
            if (lane < 32) supreg |= acc;
            if (lane == 0)
                __hip_atomic_store(&progress, c + 1, __ATOMIC_RELEASE,
                                   __HIP_MEMORY_SCOPE_WORKGROUP);
        }
    } else {
        // ---- prefetchers: wave v handles chunks v-1, v+2, v+5, ... ----
        for (int c = wave - 1; c < NCHUNK; c += 3) {
            int slot = c & (RING - 1);
            // slot free once chunk c-4 consumed: progress >= c-3; early-exit aware
            int p;
            while ((p = __hip_atomic_load(&progress, __ATOMIC_ACQUIRE,
                                          __HIP_MEMORY_SCOPE_WORKGROUP)) < c - 3)
                __builtin_amdgcn_s_sleep(1);
            if (p >= NCHUNK) break;          // resolver done: skip useless DMA tail
            const u64* src = ab + (size_t)c * 64 * NW + lane * 2;  // 16 B per lane
            u64* dst = &ring[slot][0];
            #pragma unroll
            for (int it = 0; it < 16; ++it)   // 16 x 1 KiB DMA, back-to-back, no VGPR round-trip
                gload_lds16(src + (size_t)it * 128, dst + it * 128);
            __builtin_amdgcn_s_waitcnt(0);    // drain this wave's DMA (vmcnt) before publishing
            if (lane == 0)
                __hip_atomic_store(&ready[slot], c + 1, __ATOMIC_RELEASE,
                                   __HIP_MEMORY_SCOPE_WORKGROUP);
        }
    }
    __syncthreads();

    // --- order-preserving compaction of survivors -> output rows ---
    // i0 covers [0,2048): all arrays are NPAD-sized and alive[>=K_TOP]==0 (R3 lesson).
    int i0 = tid * 8;
    unsigned int c2 = 0;
    for (int i = i0; i < i0 + 8; ++i) c2 += alive[i];
    scanbuf[tid] = c2;
    __syncthreads();
    for (int off = 1; off < 256; off <<= 1) {
        unsigned int v = scanbuf[tid];
        unsigned int addv = (tid >= off) ? scanbuf[tid - off] : 0u;
        __syncthreads();
        scanbuf[tid] = v + addv;
        __syncthreads();
    }
    unsigned int r = scanbuf[tid] - c2;
    unsigned int total = scanbuf[255];
    float* op = out + (size_t)n * POST_N * 5;
    const float4* bb = boxes + (size_t)n * K_TOP;
    for (int i = i0; i < i0 + 8; ++i) {
        if (alive[i]) {
            if (r < POST_N) {
                float4 b = bb[i];
                op[r * 5 + 0] = b.x;
                op[r * 5 + 1] = b.y;
                op[r * 5 + 2] = b.z;
                op[r * 5 + 3] = b.w;
                op[r * 5 + 4] = sls[i];
            }
            r++;
        }
    }
    unsigned int S = (total > POST_N) ? POST_N : total;
    for (unsigned int q = S + tid; q < POST_N; q += 256) {
        op[q * 5 + 0] = 0.0f;
        op[q * 5 + 1] = 0.0f;
        op[q * 5 + 2] = 0.0f;
        op[q * 5 + 3] = 0.0f;
        op[q * 5 + 4] = 0.0f;
    }
}

extern "C" void kernel_launch(void* const* d_in, const int* in_sizes, int n_in,
                              void* d_out, int out_size, void* d_ws, size_t ws_size,
                              hipStream_t stream) {
    const float* anchors = (const float*)d_in[0];
    const float* logits  = (const float*)d_in[1];
    const float* breg    = (const float*)d_in[2];
    float* out = (float*)d_out;
    char* ws = (char*)d_ws;

    // ws layout (bytes) — adj ALIASES ghist+cand (both dead before k_edges writes adj):
    // [0, 32)               cnt    : u32[8]              (zeroed each launch)
    // [64, 96)              thresh : u32[8]              (written by k_scan)
    // [128, 2097280)        ghist  : u16[8][HBLK=32][4096]   \ dead after k_scan / k_rank
    // [2097280, 2359424)    cand   : u64[8][4096]            /
    // [128, 4194432)        adj    : u64[8][2048][32]    (written by k_edges after k_rank)
    // [4194432, 4450432)    boxes  : float4[8][2000]
    // [4450432, 4514432)    scores : f32[8][2000]
    // [4514432, 4578432)    areas  : f32[8][2000]
    unsigned int* cnt     = (unsigned int*)(ws);
    unsigned int* thresh  = (unsigned int*)(ws + 64);
    unsigned short* ghist = (unsigned short*)(ws + 128);
    u64* cand             = (u64*)(ws + 2097280);
    u64* adj              = (u64*)(ws + 128);
    float4* boxes         = (float4*)(ws + 4194432);
    float* scores         = (float*)(ws + 4450432);
    float* areas          = (float*)(ws + 4514432);

    hipMemsetAsync(ws, 0, 96, stream);

    k_hist<<<dim3(HBLK, 8), 512, 0, stream>>>(logits, ghist);
    k_scan<<<8, 256, 0, stream>>>(ghist, thresh);
    k_compact<<<dim3(HBLK, 8), 512, 0, stream>>>(logits, thresh, cnt, cand);
    k_rank<<<dim3(16, 8), 512, 0, stream>>>(cand, cnt, anchors, breg, boxes, scores, areas);
    k_edges<<<dim3(NPAD / JT, NPAD / RT, 8), 256, 0, stream>>>(boxes, areas, adj);
    k_resolve<<<8, 256, 0, stream>>>(boxes, scores, adj, out);
}

// Round 14
// 197.743 us; speedup vs baseline: 1.7226x; 1.1289x over previous
//
#include <hip/hip_runtime.h>
#include <stdint.h>

#define N_BATCH 8
#define A_ 3
#define H_ 336
#define W_ 336
#define HW_ (H_*W_)        // 112896
#define M_ (A_*HW_)        // 338688
#define K_TOP 2000
#define POST_N 1000
#define NMS_THR_ 0.7f
#define NEG_ (-1e9f)
#define VALID_THR_ (-5e8f)
#define CAND_CAP 4096
#define NBINS 4096
#define BIN_SHIFT 20       // top 12 bits: sign+exp+3 mantissa
#define HBLK 32            // histogram/compact blocks per batch (256 blocks total)
#define SEG_ (M_/HBLK)     // 10584
#define XCLIP 4.135166556742356f  // log(1000/16)

#define NPAD 2048          // boxes padded to 32 chunks of 64
#define NW 32              // u64 words per adjacency row (ring UNPADDED: global_load_lds needs contiguity)
#define NCHUNK 32
#define RING 4             // ring slots (chunk c -> slot c&3)
#define RBLK 128           // candidates per k_rank block

typedef unsigned long long u64;

__device__ __forceinline__ unsigned int flip_key(float x) {
    unsigned int u = __float_as_uint(x);
    return (u & 0x80000000u) ? ~u : (u | 0x80000000u);
}
__device__ __forceinline__ float unflip_key(unsigned int k) {
    unsigned int u = (k & 0x80000000u) ? (k & 0x7fffffffu) : ~k;
    return __uint_as_float(u);
}

// Direct global->LDS DMA, 16 B/lane, no VGPR round-trip.
__device__ __forceinline__ void gload_lds16(const u64* g, u64* l) {
    __builtin_amdgcn_global_load_lds(
        (const __attribute__((address_space(1))) unsigned int*)(const void*)g,
        (__attribute__((address_space(3))) unsigned int*)(void*)l,
        16, 0, 0);
}

// ---------------- K1: per-block LDS histogram -> private u16 sub-hist; also zeroes cnt ----------------
__global__ __launch_bounds__(512) void k_hist(const float* __restrict__ logits,
                                              unsigned short* __restrict__ ghist,
                                              unsigned int* __restrict__ cnt) {
    __shared__ unsigned int h[NBINS];  // 16 KiB
    int n = blockIdx.y, b = blockIdx.x;
    if (b == 0 && threadIdx.x == 0) cnt[n] = 0;   // replaces the memset dispatch
    for (int i = threadIdx.x; i < NBINS; i += 512) h[i] = 0;
    __syncthreads();
    const float4* lp = (const float4*)(logits + (size_t)n * M_ + (size_t)b * SEG_);
    const int nq = SEG_ / 4;                 // 2646
    for (int q = threadIdx.x; q < nq; q += 512) {
        float4 v = lp[q];
        atomicAdd(&h[flip_key(v.x) >> BIN_SHIFT], 1u);
        atomicAdd(&h[flip_key(v.y) >> BIN_SHIFT], 1u);
        atomicAdd(&h[flip_key(v.z) >> BIN_SHIFT], 1u);
        atomicAdd(&h[flip_key(v.w) >> BIN_SHIFT], 1u);
    }
    __syncthreads();
    unsigned short* gp = ghist + ((size_t)n * HBLK + b) * NBINS;
    for (int i = threadIdx.x; i < NBINS; i += 512) gp[i] = (unsigned short)h[i];
}

// ---------------- K2: fused threshold-scan + compact (scan recomputed per block, L2-resident) ----------------
__global__ __launch_bounds__(512) void k_compact(const float* __restrict__ logits,
                                                 const unsigned short* __restrict__ ghist,
                                                 unsigned int* __restrict__ cnt,
                                                 u64* __restrict__ cand) {
    __shared__ unsigned int binsum[NBINS];  // 16 KiB
    __shared__ unsigned int part[512];
    __shared__ unsigned int scanb[512];
    __shared__ u64 buf[CAND_CAP];           // 32 KiB
    __shared__ unsigned int lcnt;
    __shared__ unsigned int gbase;
    __shared__ int Bsh;
    int n = blockIdx.y, b = blockIdx.x;
    int t = threadIdx.x;
    if (t == 0) lcnt = 0;
    // --- per-block threshold recompute (identical logic to the old k_scan) ---
    const unsigned short* base = ghist + (size_t)n * HBLK * NBINS;
    for (int i = t; i < NBINS; i += 512) {
        unsigned int s = 0;
        #pragma unroll 8
        for (int sb = 0; sb < HBLK; ++sb) s += base[(size_t)sb * NBINS + i];
        binsum[i] = s;
    }
    __syncthreads();
    // chunk t covers bins [NBINS-8*(t+1), NBINS-8*t) — descending chunks, 512 threads
    int hi = NBINS - 8 * t;
    int lo = hi - 8;
    unsigned int s = 0;
    for (int bb = lo; bb < hi; ++bb) s += binsum[bb];
    part[t] = s;
    scanb[t] = s;
    __syncthreads();
    for (int off = 1; off < 512; off <<= 1) {
        unsigned int v = scanb[t];
        unsigned int addv = (t >= off) ? scanb[t - off] : 0u;
        __syncthreads();
        scanb[t] = v + addv;
        __syncthreads();
    }
    unsigned int incl = scanb[t];
    unsigned int prefix = incl - part[t];
    if (prefix < K_TOP && incl >= K_TOP) {
        unsigned int acc = prefix;
        for (int bb = hi - 1; bb >= lo; --bb) {
            unsigned int c = binsum[bb];
            if (acc + c >= K_TOP) { Bsh = bb; break; }
            acc += c;
        }
    }
    __syncthreads();
    unsigned int B = (unsigned int)Bsh;
    // --- compact pass ---
    const int qbase = b * SEG_;
    const float4* lp = (const float4*)(logits + (size_t)n * M_ + (size_t)qbase);
    const int nq = SEG_ / 4;
    for (int q = t; q < nq; q += 512) {
        float4 v = lp[q];
        float vv[4] = {v.x, v.y, v.z, v.w};
        #pragma unroll
        for (int e = 0; e < 4; ++e) {
            unsigned int u = flip_key(vv[e]);
            if ((u >> BIN_SHIFT) >= B) {
                int qq = qbase + q * 4 + e;
                int a = qq / HW_;
                int hw = qq - a * HW_;
                unsigned int m = (unsigned int)(hw * A_ + a);  // score-order index
                unsigned int pos = atomicAdd(&lcnt, 1u);
                if (pos < CAND_CAP)
                    buf[pos] = ((u64)u << 32) | (unsigned int)(~m);
            }
        }
    }
    __syncthreads();
    unsigned int L = (lcnt < CAND_CAP) ? lcnt : CAND_CAP;
    if (t == 0) gbase = atomicAdd(&cnt[n], L);
    __syncthreads();
    u64* cp = cand + (size_t)n * CAND_CAP;
    for (unsigned int i = t; i < L; i += 512) {
        unsigned int pos = gbase + i;
        if (pos < CAND_CAP) cp[pos] = buf[i];
    }
}

// ---------------- K3: rank-by-counting + fused decode (4 threads per candidate, full-chip grid) ----------------
__global__ __launch_bounds__(512) void k_rank(const u64* __restrict__ cand,
                                              const unsigned int* __restrict__ cnt,
                                              const float* __restrict__ anchors,
                                              const float* __restrict__ breg,
                                              float4* __restrict__ boxes,
                                              float* __restrict__ scores,
                                              float* __restrict__ areas) {
    __shared__ u64 keys[CAND_CAP];          // 32 KiB
    __shared__ unsigned short psum[512];
    int n = blockIdx.y;
    int bx = blockIdx.x;
    unsigned int Cu = cnt[n];
    int C = (Cu < CAND_CAP) ? (int)Cu : CAND_CAP;
    if (bx * RBLK >= C) return;
    const u64* cp = cand + (size_t)n * CAND_CAP;
    for (int i = threadIdx.x; i < C; i += 512) keys[i] = cp[i];
    __syncthreads();
    int t = threadIdx.x;
    int tq = t & 3;                          // quarter within candidate
    int cl = t >> 2;                         // candidate-local index (0..127)
    int ci = bx * RBLK + cl;
    unsigned int r = 0;
    u64 ki = 0;
    if (ci < C) {
        ki = keys[ci];
        int j = tq;
        for (; j + 12 < C; j += 16) {        // 4 independent LDS broadcast reads / iter
            r += (keys[j] > ki);
            r += (keys[j + 4] > ki);
            r += (keys[j + 8] > ki);
            r += (keys[j + 12] > ki);
        }
        for (; j < C; j += 4) r += (keys[j] > ki);
    }
    psum[t] = (unsigned short)r;
    __syncthreads();
    if (tq == 0 && ci < C) {
        unsigned int rank = (unsigned int)psum[t] + psum[t + 1] + psum[t + 2] + psum[t + 3];
        if (rank < K_TOP) {
            unsigned int u = (unsigned int)(ki >> 32);
            unsigned int m = ~((unsigned int)ki);
            float logit = unflip_key(u);
            int a = (int)(m % 3u);
            int hw = (int)(m / 3u);
            float4 anc = ((const float4*)anchors)[(size_t)n * M_ + m];
            size_t rb = ((size_t)n * 12 + a * 4) * HW_ + hw;
            float dx = breg[rb];
            float dy = breg[rb + (size_t)HW_];
            float dw = breg[rb + (size_t)2 * HW_];
            float dh = breg[rb + (size_t)3 * HW_];
            float score = 1.0f / (1.0f + expf(-logit));
            float w = anc.z - anc.x + 1.0f;
            float h = anc.w - anc.y + 1.0f;
            float cx = anc.x + 0.5f * w;
            float cy = anc.y + 0.5f * h;
            dw = fminf(dw, XCLIP);
            dh = fminf(dh, XCLIP);
            float pcx = dx * w + cx;
            float pcy = dy * h + cy;
            float pw = expf(dw) * w;
            float ph = expf(dh) * h;
            float x1 = pcx - 0.5f * pw;
            float y1 = pcy - 0.5f * ph;
            float x2 = pcx + 0.5f * pw - 1.0f;
            float y2 = pcy + 0.5f * ph - 1.0f;
            x1 = fminf(fmaxf(x1, 0.0f), 1332.0f);
            y1 = fminf(fmaxf(y1, 0.0f), 799.0f);
            x2 = fminf(fmaxf(x2, 0.0f), 1332.0f);
            y2 = fminf(fmaxf(y2, 0.0f), 799.0f);
            float ww = x2 - x1 + 1.0f;
            float hh = y2 - y1 + 1.0f;
            bool keep = (ww >= 0.0f) && (hh >= 0.0f);  // MIN_SIZE = 0
            int g = n * K_TOP + (int)rank;
            boxes[g] = make_float4(x1, y1, x2, y2);
            scores[g] = keep ? score : NEG_;
            areas[g] = ww * hh;
        }
    }
}

// ---------------- K5: adjacency bitmask, UPPER-TRIANGLE tiles only ----------------
// k_resolve consumes adj[i][w] only for w >= chunk(i): the diagonal word feeds the
// in-chunk select, and sup word w is only read when resolving chunk w (rows enter sup
// at earlier chunks). Tiles entirely below the block diagonal are never read -> skip.
#define JT 512   // j's per block tile (8 u64 words)
#define RT 64    // rows per block tile (1 chunk)
__global__ __launch_bounds__(256) void k_edges(const float4* __restrict__ boxes,
                                               const float* __restrict__ areas,
                                               u64* __restrict__ adj) {
    int n = blockIdx.z;
    int by = blockIdx.y;                   // row chunk 0..31
    int bx = blockIdx.x;                   // word tile 0..3 (words bx*8..bx*8+7)
    if (by > bx * 8 + 7) return;           // all words below diagonal: never consumed
    __shared__ float4 jb[JT];
    __shared__ float ja[JT];
    int r0 = by * RT;
    int j0 = bx * JT;
    for (int j = threadIdx.x; j < JT; j += 256) {
        int jj = j0 + j;
        if (jj < K_TOP) {
            jb[j] = boxes[(size_t)n * K_TOP + jj];
            ja[j] = areas[(size_t)n * K_TOP + jj];
        } else {
            jb[j] = make_float4(-1e8f, -1e8f, -1e8f, -1e8f);  // IoU vs anything = 0
            ja[j] = 0.0f;
        }
    }
    __syncthreads();
    int i = r0 + (threadIdx.x >> 2);       // 4 threads per row
    if (i >= K_TOP) return;
    float4 bi = boxes[(size_t)n * K_TOP + i];
    float ai = areas[(size_t)n * K_TOP + i];
    #pragma unroll
    for (int rep = 0; rep < 2; ++rep) {
        int wl = (threadIdx.x & 3) + rep * 4;  // word-in-tile 0..7
        u64 bits = 0;
        int base = wl * 64;
        #pragma unroll 8
        for (int b = 0; b < 64; ++b) {
            float4 bj = jb[base + b];
            float xx1 = fmaxf(bi.x, bj.x);
            float yy1 = fmaxf(bi.y, bj.y);
            float xx2 = fminf(bi.z, bj.z);
            float yy2 = fminf(bi.w, bj.w);
            float inter = fmaxf(xx2 - xx1 + 1.0f, 0.0f) * fmaxf(yy2 - yy1 + 1.0f, 0.0f);
            float iou = inter / (ai + ja[base + b] - inter);
            bits |= ((u64)(iou > NMS_THR_)) << b;
        }
        adj[((size_t)n * NPAD + i) * NW + (j0 >> 6) + wl] = bits;
    }
}

// ---------------- K6: wave-specialized greedy NMS (ballot-Jacobi + early exit + batched sup-OR) ----------------
__global__ __launch_bounds__(256) void k_resolve(const float4* __restrict__ boxes,
                                                 const float* __restrict__ scores,
                                                 const u64* __restrict__ adj,
                                                 float* __restrict__ out) {
    __shared__ u64 ring[RING][64 * NW];     // 4 x 16 KiB = 64 KiB, CONTIGUOUS (DMA layout)
    __shared__ float sls[NPAD];             // 8 KiB
    __shared__ unsigned char alive[NPAD];   // 2 KiB (indices >= K_TOP stay 0)
    __shared__ int ready[RING];             // slot s holds chunk c when ready[s]==c+1
    __shared__ int progress;                // # chunks fully resolved
    __shared__ unsigned int scanbuf[256];
    int n = blockIdx.x;
    int tid = threadIdx.x;
    int wave = tid >> 6, lane = tid & 63;
    const u64* ab = adj + (size_t)n * NPAD * NW;

    for (int i = tid; i < NPAD; i += 256) {
        sls[i] = (i < K_TOP) ? scores[(size_t)n * K_TOP + i] : NEG_;
        alive[i] = 0;
    }
    if (tid < RING) ready[tid] = 0;
    if (tid == 0) progress = 0;
    __syncthreads();  // init visible to all waves (the ONLY barrier before the epilogue)

    if (wave == 0) {
        // ---- resolver ----
        u64 supreg = 0;  // lane w (w<32) holds suppressed-mask word w
        int survTot = 0;
        for (int c = 0; c < NCHUNK; ++c) {
            int slot = c & (RING - 1);
            while (__hip_atomic_load(&ready[slot], __ATOMIC_ACQUIRE,
                                     __HIP_MEMORY_SCOPE_WORKGROUP) != c + 1)
                __builtin_amdgcn_s_sleep(1);
            int k = lane;
            int gi = c * 64 + k;
            // symmetric adjacency: row gi word c == column k of the diag block
            u64 colk = ring[slot][k * NW + c];
            u64 supc = __shfl(supreg, c, 64);
            bool validk = (sls[gi] > VALID_THR_) && !((supc >> k) & 1ull);
            u64 below = (k == 0) ? 0ull : ((1ull << k) - 1ull);
            u64 rel = colk & below;
            // ballot-Jacobi: well-founded in k -> unique fixed point == greedy result
            bool a = validk;
            u64 am = __ballot(a);
            while (true) {
                bool anew = validk && ((am & rel) == 0ull);
                u64 am2 = __ballot(anew);
                if (am2 == am) { a = anew; break; }
                am = am2;
            }
            alive[gi] = a ? 1 : 0;
            int nal = (int)__popcll(am);
            survTot += nal;
            if (survTot >= POST_N) {
                // later boxes can't affect the first POST_N output rows -> done.
                if (lane == 0)
                    __hip_atomic_store(&progress, NCHUNK, __ATOMIC_RELEASE,
                                       __HIP_MEMORY_SCOPE_WORKGROUP);
                break;
            }
            // sup-OR: iterate set bits of am (uniform in registers), parity-split across
            // wave halves, 4 independent ds_reads per group (single waitcnt, pipelined).
            int w = lane & 31, half = lane >> 5;
            u64 acc = 0;
            u64 m = am & (half ? 0xAAAAAAAAAAAAAAAAull : 0x5555555555555555ull);
            while (m) {
                int k1 = __ffsll((unsigned long long)m) - 1; m &= m - 1;
                int k2 = k1, k3 = k1, k4 = k1;
                if (m) { k2 = __ffsll((unsigned long long)m) - 1; m &= m - 1; }
                if (m) { k3 = __ffsll((unsigned long long)m) - 1; m &= m - 1; }
                if (m) { k4 = __ffsll((unsigned long long)m) - 1; m &= m - 1; }
                u64 r1 = ring[slot][k1 * NW + w];
                u64 r2 = ring[slot][k2 * NW + w];
                u64 r3 = ring[slot][k3 * NW + w];
                u64 r4 = ring[slot][k4 * NW + w];
                acc |= r1 | r2 | r3 | r4;   // idempotent: duplicate pads harmless
            }
            acc |= __shfl_down(acc, 32);    // fold half 1 into half 0
            if (lane < 32) supreg |= acc;
            if (lane == 0)
                __hip_atomic_store(&progress, c + 1, __ATOMIC_RELEASE,
                                   __HIP_MEMORY_SCOPE_WORKGROUP);
        }
    } else {
        // ---- prefetchers: wave v handles chunks v-1, v+2, v+5, ... ----
        for (int c = wave - 1; c < NCHUNK; c += 3) {
            int slot = c & (RING - 1);
            // slot free once chunk c-4 consumed: progress >= c-3; early-exit aware
            int p;
            while ((p = __hip_atomic_load(&progress, __ATOMIC_ACQUIRE,
                                          __HIP_MEMORY_SCOPE_WORKGROUP)) < c - 3)
                __builtin_amdgcn_s_sleep(1);
            if (p >= NCHUNK) break;          // resolver done: skip useless DMA tail
            const u64* src = ab + (size_t)c * 64 * NW + lane * 2;  // 16 B per lane
            u64* dst = &ring[slot][0];
            #pragma unroll
            for (int it = 0; it < 16; ++it)   // 16 x 1 KiB DMA, back-to-back, no VGPR round-trip
                gload_lds16(src + (size_t)it * 128, dst + it * 128);
            __builtin_amdgcn_s_waitcnt(0);    // drain this wave's DMA (vmcnt) before publishing
            if (lane == 0)
                __hip_atomic_store(&ready[slot], c + 1, __ATOMIC_RELEASE,
                                   __HIP_MEMORY_SCOPE_WORKGROUP);
        }
    }
    __syncthreads();

    // --- order-preserving compaction of survivors -> output rows ---
    // i0 covers [0,2048): all arrays are NPAD-sized and alive[>=K_TOP]==0 (R3 lesson).
    int i0 = tid * 8;
    unsigned int c2 = 0;
    for (int i = i0; i < i0 + 8; ++i) c2 += alive[i];
    scanbuf[tid] = c2;
    __syncthreads();
    for (int off = 1; off < 256; off <<= 1) {
        unsigned int v = scanbuf[tid];
        unsigned int addv = (tid >= off) ? scanbuf[tid - off] : 0u;
        __syncthreads();
        scanbuf[tid] = v + addv;
        __syncthreads();
    }
    unsigned int r = scanbuf[tid] - c2;
    unsigned int total = scanbuf[255];
    float* op = out + (size_t)n * POST_N * 5;
    const float4* bb = boxes + (size_t)n * K_TOP;
    for (int i = i0; i < i0 + 8; ++i) {
        if (alive[i]) {
            if (r < POST_N) {
                float4 b = bb[i];
                op[r * 5 + 0] = b.x;
                op[r * 5 + 1] = b.y;
                op[r * 5 + 2] = b.z;
                op[r * 5 + 3] = b.w;
                op[r * 5 + 4] = sls[i];
            }
            r++;
        }
    }
    unsigned int S = (total > POST_N) ? POST_N : total;
    for (unsigned int q = S + tid; q < POST_N; q += 256) {
        op[q * 5 + 0] = 0.0f;
        op[q * 5 + 1] = 0.0f;
        op[q * 5 + 2] = 0.0f;
        op[q * 5 + 3] = 0.0f;
        op[q * 5 + 4] = 0.0f;
    }
}

extern "C" void kernel_launch(void* const* d_in, const int* in_sizes, int n_in,
                              void* d_out, int out_size, void* d_ws, size_t ws_size,
                              hipStream_t stream) {
    const float* anchors = (const float*)d_in[0];
    const float* logits  = (const float*)d_in[1];
    const float* breg    = (const float*)d_in[2];
    float* out = (float*)d_out;
    char* ws = (char*)d_ws;

    // ws layout (bytes) — adj ALIASES ghist+cand (both dead before k_edges writes adj):
    // [0, 32)               cnt    : u32[8]              (zeroed by k_hist block 0)
    // [128, 2097280)        ghist  : u16[8][HBLK=32][4096]   \ dead after k_compact / k_rank
    // [2097280, 2359424)    cand   : u64[8][4096]            /
    // [128, 4194432)        adj    : u64[8][2048][32]    (written by k_edges after k_rank;
    //                                                     below-diagonal words stay poison, never read)
    // [4194432, 4450432)    boxes  : float4[8][2000]
    // [4450432, 4514432)    scores : f32[8][2000]
    // [4514432, 4578432)    areas  : f32[8][2000]
    unsigned int* cnt     = (unsigned int*)(ws);
    unsigned short* ghist = (unsigned short*)(ws + 128);
    u64* cand             = (u64*)(ws + 2097280);
    u64* adj              = (u64*)(ws + 128);
    float4* boxes         = (float4*)(ws + 4194432);
    float* scores         = (float*)(ws + 4450432);
    float* areas          = (float*)(ws + 4514432);

    k_hist<<<dim3(HBLK, 8), 512, 0, stream>>>(logits, ghist, cnt);
    k_compact<<<dim3(HBLK, 8), 512, 0, stream>>>(logits, ghist, cnt, cand);
    k_rank<<<dim3(CAND_CAP / RBLK, 8), 512, 0, stream>>>(cand, cnt, anchors, breg,
                                                         boxes, scores, areas);
    k_edges<<<dim3(NPAD / JT, NPAD / RT, 8), 256, 0, stream>>>(boxes, areas, adj);
    k_resolve<<<8, 256, 0, stream>>>(boxes, scores, adj, out);
}

// Round 15
// 195.658 us; speedup vs baseline: 1.7410x; 1.0107x over previous
//
#include <hip/hip_runtime.h>
#include <stdint.h>

#define N_BATCH 8
#define A_ 3
#define H_ 336
#define W_ 336
#define HW_ (H_*W_)        // 112896
#define M_ (A_*HW_)        // 338688
#define K_TOP 2000
#define POST_N 1000
#define NMS_THR_ 0.7f
#define NEG_ (-1e9f)
#define VALID_THR_ (-5e8f)
#define CAND_CAP 4096
#define NBINS 4096
#define BIN_SHIFT 20       // top 12 bits: sign+exp+3 mantissa
#define HBLK 32            // histogram/compact blocks per batch (256 blocks total)
#define SEG_ (M_/HBLK)     // 10584
#define XCLIP 4.135166556742356f  // log(1000/16)

#define NPAD 2048          // boxes padded to 32 chunks of 64
#define NW 32              // u64 words per adjacency row (ring UNPADDED: global_load_lds needs contiguity)
#define NCHUNK 32
#define RING 4             // ring slots (chunk c -> slot c&3)
#define RBLK 128           // candidate slots per k_rank block

typedef unsigned long long u64;

__device__ __forceinline__ unsigned int flip_key(float x) {
    unsigned int u = __float_as_uint(x);
    return (u & 0x80000000u) ? ~u : (u | 0x80000000u);
}
__device__ __forceinline__ float unflip_key(unsigned int k) {
    unsigned int u = (k & 0x80000000u) ? (k & 0x7fffffffu) : ~k;
    return __uint_as_float(u);
}

// Direct global->LDS DMA, 16 B/lane, no VGPR round-trip.
__device__ __forceinline__ void gload_lds16(const u64* g, u64* l) {
    __builtin_amdgcn_global_load_lds(
        (const __attribute__((address_space(1))) unsigned int*)(const void*)g,
        (__attribute__((address_space(3))) unsigned int*)(void*)l,
        16, 0, 0);
}

// ---------------- K1: dual LDS sub-histograms (wave parity) -> u16 sub-hist; zeroes cnt ----------------
__global__ __launch_bounds__(512) void k_hist(const float* __restrict__ logits,
                                              unsigned short* __restrict__ ghist,
                                              unsigned int* __restrict__ cnt) {
    __shared__ unsigned int h[2][NBINS];  // 32 KiB; parity split halves same-bin atomic serialization
    int n = blockIdx.y, b = blockIdx.x;
    if (b == 0 && threadIdx.x < 2) cnt[n * 2 + threadIdx.x] = 0;  // replaces memset dispatch
    unsigned int* hf = &h[0][0];
    for (int i = threadIdx.x; i < 2 * NBINS; i += 512) hf[i] = 0;
    __syncthreads();
    int wp = (threadIdx.x >> 6) & 1;
    const float4* lp = (const float4*)(logits + (size_t)n * M_ + (size_t)b * SEG_);
    const int nq = SEG_ / 4;                 // 2646
    for (int q = threadIdx.x; q < nq; q += 512) {
        float4 v = lp[q];
        atomicAdd(&h[wp][flip_key(v.x) >> BIN_SHIFT], 1u);
        atomicAdd(&h[wp][flip_key(v.y) >> BIN_SHIFT], 1u);
        atomicAdd(&h[wp][flip_key(v.z) >> BIN_SHIFT], 1u);
        atomicAdd(&h[wp][flip_key(v.w) >> BIN_SHIFT], 1u);
    }
    __syncthreads();
    unsigned short* gp = ghist + ((size_t)n * HBLK + b) * NBINS;
    for (int i = threadIdx.x; i < NBINS; i += 512)
        gp[i] = (unsigned short)(h[0][i] + h[1][i]);
}

// ---------------- K2: fused threshold-scan + SEGMENTED compact ----------------
// hi segment (bin > B): cand[0..T), T < K_TOP guaranteed by B's definition.
// lo segment (bin == B): cand[CAND_CAP-1] growing downward. bin dominates key order,
// so every hi key > every lo key -> ranks decompose per segment (k_rank).
__global__ __launch_bounds__(512) void k_compact(const float* __restrict__ logits,
                                                 const unsigned short* __restrict__ ghist,
                                                 unsigned int* __restrict__ cnt,
                                                 u64* __restrict__ cand) {
    __shared__ unsigned int binsum[NBINS];  // 16 KiB
    __shared__ unsigned int part[512];
    __shared__ unsigned int scanb[512];
    __shared__ u64 bufHi[2048];             // 16 KiB (block hi count <= T < 2000)
    __shared__ u64 bufLo[4096];             // 32 KiB
    __shared__ unsigned int lcntHi, lcntLo, gbaseHi, gbaseLo;
    __shared__ int Bsh;
    int n = blockIdx.y, b = blockIdx.x;
    int t = threadIdx.x;
    if (t == 0) { lcntHi = 0; lcntLo = 0; }
    // --- per-block threshold recompute (identical logic to the old k_scan) ---
    const unsigned short* base = ghist + (size_t)n * HBLK * NBINS;
    for (int i = t; i < NBINS; i += 512) {
        unsigned int s = 0;
        #pragma unroll 8
        for (int sb = 0; sb < HBLK; ++sb) s += base[(size_t)sb * NBINS + i];
        binsum[i] = s;
    }
    __syncthreads();
    int hi = NBINS - 8 * t;
    int lo = hi - 8;
    unsigned int s = 0;
    for (int bb = lo; bb < hi; ++bb) s += binsum[bb];
    part[t] = s;
    scanb[t] = s;
    __syncthreads();
    for (int off = 1; off < 512; off <<= 1) {
        unsigned int v = scanb[t];
        unsigned int addv = (t >= off) ? scanb[t - off] : 0u;
        __syncthreads();
        scanb[t] = v + addv;
        __syncthreads();
    }
    unsigned int incl = scanb[t];
    unsigned int prefix = incl - part[t];
    if (prefix < K_TOP && incl >= K_TOP) {
        unsigned int acc = prefix;
        for (int bb = hi - 1; bb >= lo; --bb) {
            unsigned int c = binsum[bb];
            if (acc + c >= K_TOP) { Bsh = bb; break; }
            acc += c;
        }
    }
    __syncthreads();
    unsigned int B = (unsigned int)Bsh;
    // --- segmented compact pass ---
    const int qbase = b * SEG_;
    const float4* lp = (const float4*)(logits + (size_t)n * M_ + (size_t)qbase);
    const int nq = SEG_ / 4;
    for (int q = t; q < nq; q += 512) {
        float4 v = lp[q];
        float vv[4] = {v.x, v.y, v.z, v.w};
        #pragma unroll
        for (int e = 0; e < 4; ++e) {
            unsigned int u = flip_key(vv[e]);
            unsigned int bin = u >> BIN_SHIFT;
            if (bin >= B) {
                int qq = qbase + q * 4 + e;
                int a = qq / HW_;
                int hw = qq - a * HW_;
                unsigned int m = (unsigned int)(hw * A_ + a);  // score-order index
                u64 key = ((u64)u << 32) | (unsigned int)(~m);
                if (bin > B) {
                    unsigned int pos = atomicAdd(&lcntHi, 1u);
                    if (pos < 2048) bufHi[pos] = key;
                } else {
                    unsigned int pos = atomicAdd(&lcntLo, 1u);
                    if (pos < 4096) bufLo[pos] = key;
                }
            }
        }
    }
    __syncthreads();
    unsigned int Lhi = (lcntHi < 2048u) ? lcntHi : 2048u;
    unsigned int Llo = (lcntLo < 4096u) ? lcntLo : 4096u;
    if (t == 0) gbaseHi = atomicAdd(&cnt[n * 2], Lhi);
    if (t == 1) gbaseLo = atomicAdd(&cnt[n * 2 + 1], Llo);
    __syncthreads();
    u64* cp = cand + (size_t)n * CAND_CAP;
    for (unsigned int i = t; i < Lhi; i += 512)
        cp[gbaseHi + i] = bufHi[i];                 // global hi total = T < 2000 < CAND_CAP
    for (unsigned int i = t; i < Llo; i += 512) {
        unsigned int idx = CAND_CAP - 1u - (gbaseLo + i);
        if ((int)idx >= K_TOP) cp[idx] = bufLo[i];  // lo region never enters [0, K_TOP)
    }
}

// ---------------- K3: SEGMENTED rank-by-counting + fused decode (4 threads/candidate) ----------------
// rank(hi_i) = #{j in hi: key_j > key_i}; rank(lo_i) = T + #{j in lo: key_j > key_i}.
// Work ~ T^2 + L^2 ~= 0.5 * C^2 of the unsegmented version.
__global__ __launch_bounds__(512) void k_rank(const u64* __restrict__ cand,
                                              const unsigned int* __restrict__ cnt,
                                              const float* __restrict__ anchors,
                                              const float* __restrict__ breg,
                                              float4* __restrict__ boxes,
                                              float* __restrict__ scores,
                                              float* __restrict__ areas) {
    __shared__ u64 keys[CAND_CAP];          // 32 KiB
    __shared__ unsigned short psum[512];
    int n = blockIdx.y;
    int bx = blockIdx.x;
    unsigned int T = cnt[n * 2];                    // < 2000
    unsigned int Lc = cnt[n * 2 + 1];
    unsigned int Ls = (Lc < (unsigned int)(CAND_CAP - K_TOP)) ? Lc : (unsigned int)(CAND_CAP - K_TOP);
    int loStart = CAND_CAP - (int)Ls;
    int p0 = bx * RBLK;
    if (p0 >= (int)T && p0 + RBLK <= loStart) return;   // block fully inside the hole
    const u64* cp = cand + (size_t)n * CAND_CAP;
    for (int i = threadIdx.x; i < (int)T; i += 512) keys[i] = cp[i];
    for (int i = loStart + threadIdx.x; i < CAND_CAP; i += 512) keys[i] = cp[i];
    __syncthreads();
    int t = threadIdx.x;
    int tq = t & 3;                          // quarter within candidate
    int cl = t >> 2;                         // candidate-local index (0..127)
    int ci = p0 + cl;
    bool isHi = (ci < (int)T);
    bool isLo = (!isHi) && (ci >= loStart) && (ci < CAND_CAP);
    unsigned int r = 0;
    u64 ki = 0;
    int jb = 0, je = 0;
    unsigned int radd = 0;
    if (isHi) { ki = keys[ci]; jb = 0; je = (int)T; }
    else if (isLo) { ki = keys[ci]; jb = loStart; je = CAND_CAP; radd = T; }
    int j = jb + tq;
    for (; j + 12 < je; j += 16) {           // 4 independent LDS broadcast reads / iter
        r += (keys[j] > ki);
        r += (keys[j + 4] > ki);
        r += (keys[j + 8] > ki);
        r += (keys[j + 12] > ki);
    }
    for (; j < je; j += 4) r += (keys[j] > ki);
    psum[t] = (unsigned short)r;
    __syncthreads();
    if (tq == 0 && (isHi || isLo)) {
        unsigned int rank = radd + psum[t] + psum[t + 1] + psum[t + 2] + psum[t + 3];
        if (rank < K_TOP) {
            unsigned int u = (unsigned int)(ki >> 32);
            unsigned int m = ~((unsigned int)ki);
            float logit = unflip_key(u);
            int a = (int)(m % 3u);
            int hw = (int)(m / 3u);
            float4 anc = ((const float4*)anchors)[(size_t)n * M_ + m];
            size_t rb = ((size_t)n * 12 + a * 4) * HW_ + hw;
            float dx = breg[rb];
            float dy = breg[rb + (size_t)HW_];
            float dw = breg[rb + (size_t)2 * HW_];
            float dh = breg[rb + (size_t)3 * HW_];
            float score = 1.0f / (1.0f + expf(-logit));
            float w = anc.z - anc.x + 1.0f;
            float h = anc.w - anc.y + 1.0f;
            float cx = anc.x + 0.5f * w;
            float cy = anc.y + 0.5f * h;
            dw = fminf(dw, XCLIP);
            dh = fminf(dh, XCLIP);
            float pcx = dx * w + cx;
            float pcy = dy * h + cy;
            float pw = expf(dw) * w;
            float ph = expf(dh) * h;
            float x1 = pcx - 0.5f * pw;
            float y1 = pcy - 0.5f * ph;
            float x2 = pcx + 0.5f * pw - 1.0f;
            float y2 = pcy + 0.5f * ph - 1.0f;
            x1 = fminf(fmaxf(x1, 0.0f), 1332.0f);
            y1 = fminf(fmaxf(y1, 0.0f), 799.0f);
            x2 = fminf(fmaxf(x2, 0.0f), 1332.0f);
            y2 = fminf(fmaxf(y2, 0.0f), 799.0f);
            float ww = x2 - x1 + 1.0f;
            float hh = y2 - y1 + 1.0f;
            bool keep = (ww >= 0.0f) && (hh >= 0.0f);  // MIN_SIZE = 0
            int g = n * K_TOP + (int)rank;
            boxes[g] = make_float4(x1, y1, x2, y2);
            scores[g] = keep ? score : NEG_;
            areas[g] = ww * hh;
        }
    }
}

// ---------------- K5: adjacency bitmask, UPPER-TRIANGLE tiles only ----------------
#define JT 512   // j's per block tile (8 u64 words)
#define RT 64    // rows per block tile (1 chunk)
__global__ __launch_bounds__(256) void k_edges(const float4* __restrict__ boxes,
                                               const float* __restrict__ areas,
                                               u64* __restrict__ adj) {
    int n = blockIdx.z;
    int by = blockIdx.y;                   // row chunk 0..31
    int bx = blockIdx.x;                   // word tile 0..3 (words bx*8..bx*8+7)
    if (by > bx * 8 + 7) return;           // all words below diagonal: never consumed
    __shared__ float4 jb[JT];
    __shared__ float ja[JT];
    int r0 = by * RT;
    int j0 = bx * JT;
    for (int j = threadIdx.x; j < JT; j += 256) {
        int jj = j0 + j;
        if (jj < K_TOP) {
            jb[j] = boxes[(size_t)n * K_TOP + jj];
            ja[j] = areas[(size_t)n * K_TOP + jj];
        } else {
            jb[j] = make_float4(-1e8f, -1e8f, -1e8f, -1e8f);  // IoU vs anything = 0
            ja[j] = 0.0f;
        }
    }
    __syncthreads();
    int i = r0 + (threadIdx.x >> 2);       // 4 threads per row
    if (i >= K_TOP) return;
    float4 bi = boxes[(size_t)n * K_TOP + i];
    float ai = areas[(size_t)n * K_TOP + i];
    #pragma unroll
    for (int rep = 0; rep < 2; ++rep) {
        int wl = (threadIdx.x & 3) + rep * 4;  // word-in-tile 0..7
        u64 bits = 0;
        int base = wl * 64;
        #pragma unroll 8
        for (int b = 0; b < 64; ++b) {
            float4 bj = jb[base + b];
            float xx1 = fmaxf(bi.x, bj.x);
            float yy1 = fmaxf(bi.y, bj.y);
            float xx2 = fminf(bi.z, bj.z);
            float yy2 = fminf(bi.w, bj.w);
            float inter = fmaxf(xx2 - xx1 + 1.0f, 0.0f) * fmaxf(yy2 - yy1 + 1.0f, 0.0f);
            float iou = inter / (ai + ja[base + b] - inter);
            bits |= ((u64)(iou > NMS_THR_)) << b;
        }
        adj[((size_t)n * NPAD + i) * NW + (j0 >> 6) + wl] = bits;
    }
}

// ---------------- K6: wave-specialized greedy NMS (ballot-Jacobi + early exit + 8-wide sup-OR) ----------------
__global__ __launch_bounds__(256) void k_resolve(const float4* __restrict__ boxes,
                                                 const float* __restrict__ scores,
                                                 const u64* __restrict__ adj,
                                                 float* __restrict__ out) {
    __shared__ u64 ring[RING][64 * NW];     // 4 x 16 KiB = 64 KiB, CONTIGUOUS (DMA layout)
    __shared__ float sls[NPAD];             // 8 KiB
    __shared__ unsigned char alive[NPAD];   // 2 KiB (indices >= K_TOP stay 0)
    __shared__ int ready[RING];             // slot s holds chunk c when ready[s]==c+1
    __shared__ int progress;                // # chunks fully resolved
    __shared__ unsigned int scanbuf[256];
    int n = blockIdx.x;
    int tid = threadIdx.x;
    int wave = tid >> 6, lane = tid & 63;
    const u64* ab = adj + (size_t)n * NPAD * NW;

    for (int i = tid; i < NPAD; i += 256) {
        sls[i] = (i < K_TOP) ? scores[(size_t)n * K_TOP + i] : NEG_;
        alive[i] = 0;
    }
    if (tid < RING) ready[tid] = 0;
    if (tid == 0) progress = 0;
    __syncthreads();  // init visible to all waves (the ONLY barrier before the epilogue)

    if (wave == 0) {
        // ---- resolver ----
        u64 supreg = 0;  // lane w (w<32) holds suppressed-mask word w
        int survTot = 0;
        for (int c = 0; c < NCHUNK; ++c) {
            int slot = c & (RING - 1);
            while (__hip_atomic_load(&ready[slot], __ATOMIC_ACQUIRE,
                                     __HIP_MEMORY_SCOPE_WORKGROUP) != c + 1)
                __builtin_amdgcn_s_sleep(1);
            int k = lane;
            int gi = c * 64 + k;
            // symmetric adjacency: row gi word c == column k of the diag block
            u64 colk = ring[slot][k * NW + c];
            u64 supc = __shfl(supreg, c, 64);
            bool validk = (sls[gi] > VALID_THR_) && !((supc >> k) & 1ull);
            u64 below = (k == 0) ? 0ull : ((1ull << k) - 1ull);
            u64 rel = colk & below;
            // ballot-Jacobi: well-founded in k -> unique fixed point == greedy result
            bool a = validk;
            u64 am = __ballot(a);
            while (true) {
                bool anew = validk && ((am & rel) == 0ull);
                u64 am2 = __ballot(anew);
                if (am2 == am) { a = anew; break; }
                am = am2;
            }
            alive[gi] = a ? 1 : 0;
            int nal = (int)__popcll(am);
            survTot += nal;
            if (survTot >= POST_N) {
                // later boxes can't affect the first POST_N output rows -> done.
                if (lane == 0)
                    __hip_atomic_store(&progress, NCHUNK, __ATOMIC_RELEASE,
                                       __HIP_MEMORY_SCOPE_WORKGROUP);
                break;
            }
            // sup-OR: set bits of am (register-uniform), parity-split across wave halves,
            // 8 independent ds_reads per group before one waitcnt (idempotent dup pads).
            int w = lane & 31, half = lane >> 5;
            u64 acc = 0;
            u64 m = am & (half ? 0xAAAAAAAAAAAAAAAAull : 0x5555555555555555ull);
            while (m) {
                int kk[8];
                kk[0] = __ffsll((unsigned long long)m) - 1; m &= m - 1;
                #pragma unroll
                for (int e = 1; e < 8; ++e) {
                    kk[e] = m ? (__ffsll((unsigned long long)m) - 1) : kk[0];
                    if (m) m &= m - 1;
                }
                u64 r0 = ring[slot][kk[0] * NW + w];
                u64 r1 = ring[slot][kk[1] * NW + w];
                u64 r2 = ring[slot][kk[2] * NW + w];
                u64 r3 = ring[slot][kk[3] * NW + w];
                u64 r4 = ring[slot][kk[4] * NW + w];
                u64 r5 = ring[slot][kk[5] * NW + w];
                u64 r6 = ring[slot][kk[6] * NW + w];
                u64 r7 = ring[slot][kk[7] * NW + w];
                acc |= (r0 | r1) | (r2 | r3) | ((r4 | r5) | (r6 | r7));
            }
            acc |= __shfl_down(acc, 32);    // fold half 1 into half 0
            if (lane < 32) supreg |= acc;
            if (lane == 0)
                __hip_atomic_store(&progress, c + 1, __ATOMIC_RELEASE,
                                   __HIP_MEMORY_SCOPE_WORKGROUP);
        }
    } else {
        // ---- prefetchers: wave v handles chunks v-1, v+2, v+5, ... ----
        for (int c = wave - 1; c < NCHUNK; c += 3) {
            int slot = c & (RING - 1);
            int p;
            while ((p = __hip_atomic_load(&progress, __ATOMIC_ACQUIRE,
                                          __HIP_MEMORY_SCOPE_WORKGROUP)) < c - 3)
                __builtin_amdgcn_s_sleep(1);
            if (p >= NCHUNK) break;          // resolver done: skip useless DMA tail
            const u64* src = ab + (size_t)c * 64 * NW + lane * 2;  // 16 B per lane
            u64* dst = &ring[slot][0];
            #pragma unroll
            for (int it = 0; it < 16; ++it)   // 16 x 1 KiB DMA, back-to-back
                gload_lds16(src + (size_t)it * 128, dst + it * 128);
            __builtin_amdgcn_s_waitcnt(0);    // drain this wave's DMA before publishing
            if (lane == 0)
                __hip_atomic_store(&ready[slot], c + 1, __ATOMIC_RELEASE,
                                   __HIP_MEMORY_SCOPE_WORKGROUP);
        }
    }
    __syncthreads();

    // --- order-preserving compaction of survivors -> output rows ---
    // i0 covers [0,2048): all arrays are NPAD-sized and alive[>=K_TOP]==0 (R3 lesson).
    int i0 = tid * 8;
    unsigned int c2 = 0;
    for (int i = i0; i < i0 + 8; ++i) c2 += alive[i];
    scanbuf[tid] = c2;
    __syncthreads();
    for (int off = 1; off < 256; off <<= 1) {
        unsigned int v = scanbuf[tid];
        unsigned int addv = (tid >= off) ? scanbuf[tid - off] : 0u;
        __syncthreads();
        scanbuf[tid] = v + addv;
        __syncthreads();
    }
    unsigned int r = scanbuf[tid] - c2;
    unsigned int total = scanbuf[255];
    float* op = out + (size_t)n * POST_N * 5;
    const float4* bb = boxes + (size_t)n * K_TOP;
    for (int i = i0; i < i0 + 8; ++i) {
        if (alive[i]) {
            if (r < POST_N) {
                float4 b = bb[i];
                op[r * 5 + 0] = b.x;
                op[r * 5 + 1] = b.y;
                op[r * 5 + 2] = b.z;
                op[r * 5 + 3] = b.w;
                op[r * 5 + 4] = sls[i];
            }
            r++;
        }
    }
    unsigned int S = (total > POST_N) ? POST_N : total;
    for (unsigned int q = S + tid; q < POST_N; q += 256) {
        op[q * 5 + 0] = 0.0f;
        op[q * 5 + 1] = 0.0f;
        op[q * 5 + 2] = 0.0f;
        op[q * 5 + 3] = 0.0f;
        op[q * 5 + 4] = 0.0f;
    }
}

extern "C" void kernel_launch(void* const* d_in, const int* in_sizes, int n_in,
                              void* d_out, int out_size, void* d_ws, size_t ws_size,
                              hipStream_t stream) {
    const float* anchors = (const float*)d_in[0];
    const float* logits  = (const float*)d_in[1];
    const float* breg    = (const float*)d_in[2];
    float* out = (float*)d_out;
    char* ws = (char*)d_ws;

    // ws layout (bytes) — adj ALIASES ghist+cand (both dead before k_edges writes adj):
    // [0, 64)               cnt    : u32[8][2]           (zeroed by k_hist block 0: hi/lo counters)
    // [128, 2097280)        ghist  : u16[8][HBLK=32][4096]   \ dead after k_compact / k_rank
    // [2097280, 2359424)    cand   : u64[8][4096]            /   (hi seg up, lo seg down)
    // [128, 4194432)        adj    : u64[8][2048][32]    (written by k_edges after k_rank;
    //                                                     below-diagonal words stay poison, never read)
    // [4194432, 4450432)    boxes  : float4[8][2000]
    // [4450432, 4514432)    scores : f32[8][2000]
    // [4514432, 4578432)    areas  : f32[8][2000]
    unsigned int* cnt     = (unsigned int*)(ws);
    unsigned short* ghist = (unsigned short*)(ws + 128);
    u64* cand             = (u64*)(ws + 2097280);
    u64* adj              = (u64*)(ws + 128);
    float4* boxes         = (float4*)(ws + 4194432);
    float* scores         = (float*)(ws + 4450432);
    float* areas          = (float*)(ws + 4514432);

    k_hist<<<dim3(HBLK, 8), 512, 0, stream>>>(logits, ghist, cnt);
    k_compact<<<dim3(HBLK, 8), 512, 0, stream>>>(logits, ghist, cnt, cand);
    k_rank<<<dim3(CAND_CAP / RBLK, 8), 512, 0, stream>>>(cand, cnt, anchors, breg,
                                                         boxes, scores, areas);
    k_edges<<<dim3(NPAD / JT, NPAD / RT, 8), 256, 0, stream>>>(boxes, areas, adj);
    k_resolve<<<8, 256, 0, stream>>>(boxes, scores, adj, out);
}